// Round 11
// baseline (258.817 us; speedup 1.0000x reference)
//
#include <hip/hip_runtime.h>
#include <cmath>

typedef unsigned long long u64;

#define PRE_TOPN 12000
#define POST_TOPN 2000
#define SORTN 32768
#define TILE 2048              // local-sort tile
#define NTILE (SORTN / TILE)   // 16 tiles per batch
#define NBLK 188               // 64-bit column blocks covering 12032
#define PADN (NBLK * 64)       // 12032
// ROW-MAJOR triangular bitmap: row r stores words for col-blocks
// cb in [r/64, NBLK) contiguously at rowoff(r). Total words per batch:
#define TRI_WORDS (32 * (NBLK - 1) * NBLK + NBLK * 64)  // 1,137,024
#define MASK_WORDS 192         // 188 used, padded
#define NPF 22                 // crew preload regs (stride-3 worst case: 3*21=63)

// Light workgroup barrier: orders LDS (lgkmcnt) but lets global loads stay
// in flight across the barrier.
#define WG_SYNC() asm volatile("s_waitcnt lgkmcnt(0)\n\ts_barrier" ::: "memory")

__device__ __forceinline__ int rowoff(int r) {
    int rb = r >> 6;
    int q = r & 63;
    return r * NBLK - (32 * rb * (rb - 1) + q * rb);
}

// ---------------------------------------------------------------------------
// Kernel 1: decode boxes (exact fp32 op order, no FMA contraction, exp via
// double) and pack sort keys. key = (~score_bits)<<32 | idx.
// Also resets the per-batch NMS progress state (kcnt/done) for this launch.
// ---------------------------------------------------------------------------
__global__ void decode_pack(const float* __restrict__ anchors,
                            const float* __restrict__ deltas,
                            const float* __restrict__ scores,
                            float* __restrict__ boxes,
                            u64* __restrict__ keys,
                            int* __restrict__ kcnt,
                            int* __restrict__ done,
                            int N) {
#pragma clang fp contract(off)
    int n = blockIdx.x * blockDim.x + threadIdx.x;
    int b = blockIdx.y;
    if (kcnt != nullptr && blockIdx.x == 0 && threadIdx.x == 0) {
        kcnt[b] = 0;
        done[b] = 0;
    }
    if (n >= SORTN) return;
    u64* kb = keys + (size_t)b * SORTN;
    if (n < N) {
        float a0 = anchors[n * 4 + 0];
        float a1 = anchors[n * 4 + 1];
        float a2 = anchors[n * 4 + 2];
        float a3 = anchors[n * 4 + 3];
        float w = (a2 - a0) + 1.0f;
        float h = (a3 - a1) + 1.0f;
        float cx = a0 + 0.5f * w;
        float cy = a1 + 0.5f * h;
        const float* d = deltas + ((size_t)b * N + n) * 4;
        float dx = d[0], dy = d[1], dw = d[2], dh = d[3];
        float px = cx + w * dx;
        float py = cy + h * dy;
        float pw = (float)::exp((double)dw) * w;
        float ph = (float)::exp((double)dh) * h;
        float* bb = boxes + ((size_t)b * N + n) * 4;
        bb[0] = px - 0.5f * pw;
        bb[1] = py - 0.5f * ph;
        bb[2] = px + 0.5f * (pw - 2.0f);
        bb[3] = py + 0.5f * (ph - 2.0f);
        unsigned int sb = __float_as_uint(scores[(size_t)b * N + n]);
        kb[n] = ((u64)(~sb) << 32) | (u64)(unsigned int)n;
    } else {
        kb[n] = ~0ULL;
    }
}

// ---------------------------------------------------------------------------
// Hybrid bitonic sort: 2048-element tiles + register-orbit fused global steps.
// ---------------------------------------------------------------------------
__global__ __launch_bounds__(256) void bitonic_local_sort(u64* __restrict__ keys) {
    __shared__ u64 sk[TILE];
    int tile = blockIdx.x;
    u64* kb = keys + (size_t)tile * TILE;
    int base = (tile % NTILE) * TILE;
    for (int i = threadIdx.x; i < TILE; i += 256) sk[i] = kb[i];
    __syncthreads();
    for (int k = 2; k <= TILE; k <<= 1) {
        for (int j = k >> 1; j > 0; j >>= 1) {
            for (int t = threadIdx.x; t < TILE / 2; t += 256) {
                int i = ((t & ~(j - 1)) << 1) | (t & (j - 1));
                int ixj = i | j;
                u64 a = sk[i];
                u64 c = sk[ixj];
                bool up = (((base + i) & k) == 0);
                if ((a > c) == up) { sk[i] = c; sk[ixj] = a; }
            }
            __syncthreads();
        }
    }
    for (int i = threadIdx.x; i < TILE; i += 256) kb[i] = sk[i];
}

template<int G>
__global__ __launch_bounds__(256) void bitonic_fused_global(u64* __restrict__ keys) {
    const int K = TILE << G;
    const int M = 1 << G;
    int nbase = SORTN >> G;                  // base indices per batch
    int t = blockIdx.x * 256 + threadIdx.x;  // over B*nbase
    int b = t / nbase;
    int r = t % nbase;
    int low = r & (TILE - 1);
    int high = (r >> 11) << (11 + G);
    int base = high | low;
    u64* kb = keys + (size_t)b * SORTN;
    bool up = ((base & K) == 0);
    u64 e[M];
#pragma unroll
    for (int m = 0; m < M; ++m) e[m] = kb[base + (m << 11)];
#pragma unroll
    for (int s = G - 1; s >= 0; --s) {
        const int bit = 1 << s;
#pragma unroll
        for (int m = 0; m < M; ++m) {
            if (!(m & bit)) {
                u64 a = e[m], c = e[m | bit];
                if ((a > c) == up) { e[m] = c; e[m | bit] = a; }
            }
        }
    }
#pragma unroll
    for (int m = 0; m < M; ++m) kb[base + (m << 11)] = e[m];
}

__global__ __launch_bounds__(256) void bitonic_local_merge(u64* __restrict__ keys, int k) {
    __shared__ u64 sk[TILE];
    int tile = blockIdx.x;
    u64* kb = keys + (size_t)tile * TILE;
    int base = (tile % NTILE) * TILE;
    bool up = ((base & k) == 0);
    for (int i = threadIdx.x; i < TILE; i += 256) sk[i] = kb[i];
    __syncthreads();
    for (int j = TILE / 2; j > 0; j >>= 1) {
        for (int t = threadIdx.x; t < TILE / 2; t += 256) {
            int i = ((t & ~(j - 1)) << 1) | (t & (j - 1));
            int ixj = i | j;
            u64 a = sk[i];
            u64 c = sk[ixj];
            if ((a > c) == up) { sk[i] = c; sk[ixj] = a; }
        }
        __syncthreads();
    }
    for (int i = threadIdx.x; i < TILE; i += 256) kb[i] = sk[i];
}

// ---------------------------------------------------------------------------
// Gather sorted top-PADN boxes. Pad rows get far-away degenerate boxes.
// ---------------------------------------------------------------------------
__global__ void gather_sorted(const float* __restrict__ boxes,
                              const u64* __restrict__ keys,
                              float4* __restrict__ sbox, int N) {
    int r = blockIdx.x * 256 + threadIdx.x;
    int b = blockIdx.y;
    if (r >= PADN) return;
    float4 v;
    if (r < PRE_TOPN) {
        u64 key = keys[(size_t)b * SORTN + r];
        int n = (int)(unsigned)(key & 0xffffffffULL);
        v = ((const float4*)boxes)[(size_t)b * N + n];
    } else {
        v = make_float4(-4e8f, -4e8f, -4e8f, -4e8f);
    }
    sbox[(size_t)b * PADN + r] = v;
}

// ---------------------------------------------------------------------------
// Exact-f32 suppression predicate (bit-identical to the f64 reference test).
// ---------------------------------------------------------------------------
__device__ __forceinline__ void iou_bit(float4 me, float ar, float4 cj, float aj,
                                        int j, unsigned& lo, unsigned& hi, int& tie) {
#pragma clang fp contract(off)
    float xx1 = fmaxf(me.x, cj.x);
    float yy1 = fmaxf(me.y, cj.y);
    float xx2 = fminf(me.z, cj.z);
    float yy2 = fminf(me.w, cj.w);
    float w = fmaxf((xx2 - xx1) + 1.0f, 0.0f);
    float h = fmaxf((yy2 - yy1) + 1.0f, 0.0f);
    float inter = w * h;
    float un = (ar + aj) - inter;
    float t = __builtin_fmaf(-0.7f, un, inter);
    float u25 = un * 0x1p-25f;
    unsigned sup = (t > u25) ? 1u : 0u;
    tie |= (t == u25) ? 1 : 0;
    if (j < 32) lo |= sup << j;
    else        hi |= sup << (j - 32);
}

__device__ __attribute__((noinline)) u64 slow_word(float4 me, float ar,
                                                   const float4* cbox,
                                                   const float* carea) {
#pragma clang fp contract(off)
    const double MD = (double)0.7f + 0x1p-25;   // exact midpoint multiplier
    u64 word = 0;
    for (int j = 0; j < 64; ++j) {
        float4 cj = cbox[j];
        float aj = carea[j];
        float xx1 = fmaxf(me.x, cj.x);
        float yy1 = fmaxf(me.y, cj.y);
        float xx2 = fminf(me.z, cj.z);
        float yy2 = fminf(me.w, cj.w);
        float w = fmaxf((xx2 - xx1) + 1.0f, 0.0f);
        float h = fmaxf((yy2 - yy1) + 1.0f, 0.0f);
        float inter = w * h;
        float un = (ar + aj) - inter;
        bool sup = ((double)inter >= MD * (double)un);
        word |= ((u64)sup) << j;
    }
    return word;
}

// ---------------------------------------------------------------------------
// Build ROW-MAJOR suppression bitmap for col-block pairs [pair0, ...).
// Diagonal words -> diag[]; near-diagonal words (r, rb+1) -> sd1[] and
// (r, rb+2) -> sd2[] (contiguous), so the scan's wave0 has NO pick-dependent
// loads: its 2-deep delta pipeline reads prefetched sd registers.
// ---------------------------------------------------------------------------
__global__ __launch_bounds__(256) void build_bitmap(const float4* __restrict__ sbox,
                                                    u64* __restrict__ bitmap,
                                                    u64* __restrict__ diag,
                                                    u64* __restrict__ sd1,
                                                    u64* __restrict__ sd2,
                                                    const int* __restrict__ done,
                                                    int pair0) {
    int pair = pair0 + blockIdx.x;   // covers cbs 2*pair, 2*pair+1
    int chunk = blockIdx.y;          // 256-row chunk
    int b = blockIdx.z;
    if (done[b]) return;
    if (2 * chunk > pair) return;    // chunk's first row >= (2p+2)*64 -> empty
    int tid = threadIdx.x;
    int w = tid & 1;
    int cb = pair * 2 + w;
    int lim = (cb + 1) * 64;         // rows with words in column-block cb

    __shared__ float4 cbox[2][64];
    __shared__ float carea[2][64];
    const float4* sb = sbox + (size_t)b * PADN;
    if (tid < 128) {
        int which = tid >> 6, j = tid & 63;
        float4 c4 = sb[(pair * 2 + which) * 64 + j];
        cbox[which][j] = c4;
        carea[which][j] = ((c4.z - c4.x) + 1.0f) * ((c4.w - c4.y) + 1.0f);
    }
    int rl = tid >> 1;               // 0..127
    int r1 = chunk * 256 + rl;       // <= 46*256+127 = 11903 < PADN
    int r2 = r1 + 128;               // <= 12031 < PADN
    bool a1 = (r1 < lim);
    bool a2 = (r2 < lim);
    float4 me1 = sb[r1];
    float4 me2 = sb[r2];
    float ar1 = ((me1.z - me1.x) + 1.0f) * ((me1.w - me1.y) + 1.0f);
    float ar2 = ((me2.z - me2.x) + 1.0f) * ((me2.w - me2.y) + 1.0f);
    __syncthreads();

    u64* dgb = diag + (size_t)b * PADN;
    u64* sd1b = sd1 + (size_t)b * PADN;
    u64* sd2b = sd2 + (size_t)b * PADN;
    if (a1) {
        unsigned lo1 = 0, hi1 = 0;
        int tie1 = 0;
#pragma unroll
        for (int j = 0; j < 64; ++j) {
            iou_bit(me1, ar1, cbox[w][j], carea[w][j], j, lo1, hi1, tie1);
        }
        u64 w1 = ((u64)hi1 << 32) | lo1;
        if (__builtin_expect(tie1, 0)) w1 = slow_word(me1, ar1, cbox[w], carea[w]);
        int rbr = r1 >> 6;
        if (cb == rbr) {                             // diagonal block word
            w1 &= ~((2ULL << (r1 - cb * 64)) - 1ULL);
            dgb[r1] = w1;
        } else if (cb == rbr + 1) sd1b[r1] = w1;
        else if (cb == rbr + 2)   sd2b[r1] = w1;
        bitmap[(size_t)b * TRI_WORDS + rowoff(r1) + (cb - rbr)] = w1;
    }
    if (a2) {
        unsigned lo2 = 0, hi2 = 0;
        int tie2 = 0;
#pragma unroll
        for (int j = 0; j < 64; ++j) {
            iou_bit(me2, ar2, cbox[w][j], carea[w][j], j, lo2, hi2, tie2);
        }
        u64 w2 = ((u64)hi2 << 32) | lo2;
        if (__builtin_expect(tie2, 0)) w2 = slow_word(me2, ar2, cbox[w], carea[w]);
        int rbr = r2 >> 6;
        if (cb == rbr) {
            w2 &= ~((2ULL << (r2 - cb * 64)) - 1ULL);
            dgb[r2] = w2;
        } else if (cb == rbr + 1) sd1b[r2] = w2;
        else if (cb == rbr + 2)   sd2b[r2] = w2;
        bitmap[(size_t)b * TRI_WORDS + rowoff(r2) + (cb - rbr)] = w2;
    }
}

// ---------------------------------------------------------------------------
// DPP helpers: 16-lane OR-reduce, wave total via readlanes, and the
// canonical 64-lane inclusive prefix-OR scan.
// ---------------------------------------------------------------------------
__device__ __forceinline__ unsigned dpp_or16(unsigned v) {
    v |= (unsigned)__builtin_amdgcn_update_dpp(0, (int)v, 0xB1, 0xF, 0xF, true);   // quad_perm {1,0,3,2}
    v |= (unsigned)__builtin_amdgcn_update_dpp(0, (int)v, 0x4E, 0xF, 0xF, true);   // quad_perm {2,3,0,1}
    v |= (unsigned)__builtin_amdgcn_update_dpp(0, (int)v, 0x141, 0xF, 0xF, true);  // row_half_mirror
    v |= (unsigned)__builtin_amdgcn_update_dpp(0, (int)v, 0x140, 0xF, 0xF, true);  // row_mirror
    return v;
}

__device__ __forceinline__ unsigned wave_or_from_rows(unsigned rowred) {
    unsigned a = (unsigned)__builtin_amdgcn_readlane((int)rowred, 0) |
                 (unsigned)__builtin_amdgcn_readlane((int)rowred, 16);
    unsigned c = (unsigned)__builtin_amdgcn_readlane((int)rowred, 32) |
                 (unsigned)__builtin_amdgcn_readlane((int)rowred, 48);
    return a | c;
}

__device__ __forceinline__ unsigned wave_incl_prefix_or(unsigned v) {
    v |= (unsigned)__builtin_amdgcn_update_dpp(0, (int)v, 0x111, 0xF, 0xF, true);  // row_shr:1
    v |= (unsigned)__builtin_amdgcn_update_dpp(0, (int)v, 0x112, 0xF, 0xF, true);  // row_shr:2
    v |= (unsigned)__builtin_amdgcn_update_dpp(0, (int)v, 0x114, 0xF, 0xF, true);  // row_shr:4
    v |= (unsigned)__builtin_amdgcn_update_dpp(0, (int)v, 0x118, 0xF, 0xF, true);  // row_shr:8
    v |= (unsigned)__builtin_amdgcn_update_dpp(0, (int)v, 0x142, 0xA, 0xF, true);  // row_bcast:15 -> rows 1,3
    v |= (unsigned)__builtin_amdgcn_update_dpp(0, (int)v, 0x143, 0xC, 0xF, true);  // row_bcast:31 -> rows 2,3
    return v;
}

// ---------------------------------------------------------------------------
// Resumable scan, round-16 = round-15 lag-2 pipeline with:
//  (a) wave0 fully load-free on the pick path: cur1/cur2 come from the
//      prefetched sd1/sd2 registers (word(p,rb+1), word(p,rb+2)) instead of
//      pick-dependent bm loads -- the last exposed latency on the critical
//      wave is gone;
//  (b) 512 threads (8 waves): 7 crew waves fully utilized (stage tails are
//      <=66 cols). len<=64: 7 stripes x 1 col-segment (stride 7);
//      len>64: {4 x stride-4 seg0, 3 x stride-3 seg1}. NPF=22 preload regs
//      (static idx, idempotent clamp) cover npp<=64 for stride 3.
// Semantics identical to rounds 7-15.
// ---------------------------------------------------------------------------
__global__ __launch_bounds__(512) void scan_nms(const float4* __restrict__ sbox,
                                                const u64* __restrict__ bitmap,
                                                const u64* __restrict__ diag,
                                                const u64* __restrict__ sd1,
                                                const u64* __restrict__ sd2,
                                                float* __restrict__ out,
                                                u64* __restrict__ S_g,
                                                int* __restrict__ picks_g,
                                                int* __restrict__ kcnt,
                                                int* __restrict__ done,
                                                int rb0, int rb1) {
    int b = blockIdx.x;
    if (done[b]) return;
    int tid = threadIdx.x;
    int lane = tid & 63;
    int wv = tid >> 6;                     // 0..7
    __shared__ u64 s_S[MASK_WORDS];        // 1.5 KB running suppression mask
    __shared__ int s_pp[POST_TOPN];        // 8 KB committed pick rows
    __shared__ int s_prevpicks[2][64];
    __shared__ int s_np[2];
    __shared__ int s_K;

    u64* Sg = S_g + (size_t)b * MASK_WORDS;
    int* pg = picks_g + (size_t)b * POST_TOPN;
    int K0 = kcnt[b];
    if (tid == 0) s_K = K0;
    if (tid < 2) s_np[tid] = 0;
    if (tid < MASK_WORDS) s_S[tid] = (tid < NBLK && rb0 > 0) ? Sg[tid] : 0ULL;
    for (int t = tid; t < K0; t += 512) s_pp[t] = pg[t];
    WG_SYNC();

    const u64* bm = bitmap + (size_t)b * TRI_WORDS;
    const u64* dgb = diag + (size_t)b * PADN;
    const u64* sd1b = sd1 + (size_t)b * PADN;
    const u64* sd2b = sd2 + (size_t)b * PADN;
    const float4* sbb = sbox + (size_t)b * PADN;

    u64 myrow = 0, mysd1 = 0, mysd2 = 0;
    u64 cur1 = 0, cur2 = 0, pend2 = 0;     // wave0 2-deep delta pipeline
    u64 pf[NPF];                           // crew preload regs (static idx)
#pragma unroll
    for (int t = 0; t < NPF; ++t) pf[t] = 0;
    bool haveC = false, actC = false;
    u64 amaskC = 0;
    int colC = 0;
    float4 mybox = make_float4(0.f, 0.f, 0.f, 0.f);

    if (wv == 0) {
        // prologue diag/sd rows + box for rb0 (coalesced; overlaps catch-up)
        int r = rb0 * 64 + lane;
        myrow = dgb[r];
        mysd1 = sd1b[r];
        mysd2 = sd2b[r];
        mybox = sbb[r];
    } else if (rb0 > 0 && K0 > 0) {
        // ---- CATCH-UP: cols [rb0, rb1) x all K0 prior picks ----
        int width = rb1 - rb0;             // <= 128 by stage construction
        int nseg2 = (width + 63) >> 6;     // 1 or 2
        int w = wv - 1;                    // 0..6
        int s2, str, nstr;
        if (nseg2 == 2) { s2 = (w >= 4) ? 1 : 0; str = s2 ? (w - 4) : w; nstr = s2 ? 3 : 4; }
        else            { s2 = 0; str = w; nstr = 7; }
        int ce = s2 * 64 + lane;
        bool act = (ce < width);
        u64 amask = act ? ~0ULL : 0ULL;
        int cb = rb0 + ce;
        int cbc = act ? cb : rb0;
        u64 acc = 0;
        int last = K0 - 1;
        for (int q = str; q < K0; q += 8 * nstr) {
            int q0 = q;
            int q1 = q + nstr;     if (q1 > last) q1 = q0;
            int q2 = q + 2 * nstr; if (q2 > last) q2 = q0;
            int q3 = q + 3 * nstr; if (q3 > last) q3 = q0;
            int q4 = q + 4 * nstr; if (q4 > last) q4 = q0;
            int q5 = q + 5 * nstr; if (q5 > last) q5 = q0;
            int q6 = q + 6 * nstr; if (q6 > last) q6 = q0;
            int q7 = q + 7 * nstr; if (q7 > last) q7 = q0;
            int p0 = s_pp[q0], p1 = s_pp[q1], p2 = s_pp[q2], p3 = s_pp[q3];
            int p4 = s_pp[q4], p5 = s_pp[q5], p6 = s_pp[q6], p7 = s_pp[q7];
            u64 v0 = bm[rowoff(p0) + (cbc - (p0 >> 6))];
            u64 v1 = bm[rowoff(p1) + (cbc - (p1 >> 6))];
            u64 v2 = bm[rowoff(p2) + (cbc - (p2 >> 6))];
            u64 v3 = bm[rowoff(p3) + (cbc - (p3 >> 6))];
            u64 v4 = bm[rowoff(p4) + (cbc - (p4 >> 6))];
            u64 v5 = bm[rowoff(p5) + (cbc - (p5 >> 6))];
            u64 v6 = bm[rowoff(p6) + (cbc - (p6 >> 6))];
            u64 v7 = bm[rowoff(p7) + (cbc - (p7 >> 6))];
            acc |= ((v0 | v1) | (v2 | v3)) | ((v4 | v5) | (v6 | v7));
        }
        acc &= amask;
        if (act && acc) atomicOr(&s_S[cb], acc);
    }
    WG_SYNC();

    int rb = rb0;
    for (; rb < rb1; ++rb) {
        int K = s_K;                       // uniform (post-barrier)
        if (K >= POST_TOPN) break;
        int base = rb * 64;
        bool havenext = (rb + 1 < rb1);
        bool havenext2 = (rb + 2 < rb1);
        int pq = (rb + 1) & 1;             // parity of picks of rb-1

        if (wv == 0) {
            // early prefetch of next diag/sd rows + box (coalesced)
            u64 nrow = 0, nsd1 = 0, nsd2 = 0;
            float4 nbox = make_float4(0.f, 0.f, 0.f, 0.f);
            if (havenext) {
                int rn = (rb + 1) * 64 + lane;
                nrow = dgb[rn];
                nsd1 = sd1b[rn];
                nsd2 = sd2b[rn];
                nbox = sbb[rn];
            }
            // delta: picks(rb-1)@rb (cur1) | picks(rb-2)@rb (cur2)
            u64 dd = cur1 | cur2;
            unsigned rlo = dpp_or16((unsigned)(dd & 0xffffffffULL));
            unsigned rhi = dpp_or16((unsigned)(dd >> 32));
            u64 dtot = ((u64)wave_or_from_rows(rhi) << 32) | wave_or_from_rows(rlo);
            u64 t4 = s_S[rb] | dtot;
            if (rb == NBLK - 1) t4 |= 0xFFFFFFFF00000000ULL;   // pad rows >= 12000
            unsigned tlo = (unsigned)__builtin_amdgcn_readfirstlane((int)(t4 & 0xffffffffULL));
            unsigned thi = (unsigned)__builtin_amdgcn_readfirstlane((int)(t4 >> 32));
            u64 alive = ~(((u64)thi << 32) | tlo);
            unsigned mlo = (unsigned)(myrow & 0xffffffffULL);
            unsigned mhi = (unsigned)(myrow >> 32);

            // ---- frontier-batched greedy (exact serial-greedy pick set) ----
            u64 picks = 0;
            int round = 0;
            while (alive) {
                if (round >= 8) {
                    // serial fallback for pathological chain depth
                    u64 cur = alive;
                    while (cur) {
                        int i = (int)__builtin_ctzll(cur);
                        picks |= 1ULL << i;
                        unsigned rl = (unsigned)__builtin_amdgcn_readlane((int)mlo, i);
                        unsigned rh = (unsigned)__builtin_amdgcn_readlane((int)mhi, i);
                        u64 row = ((u64)rh << 32) | rl;
                        alive &= ~row;
                        cur = alive & ~((2ULL << i) - 1ULL);
                    }
                    break;
                }
                bool isal = ((alive >> lane) & 1ULL) != 0ULL;
                unsigned clo = isal ? mlo : 0u;
                unsigned chi = isal ? mhi : 0u;
                unsigned plo = wave_incl_prefix_or(clo);
                unsigned phi = wave_incl_prefix_or(chi);
                u64 pre = ((u64)phi << 32) | plo;
                bool infront = isal && (((pre >> lane) & 1ULL) == 0ULL);
                u64 front = __ballot(infront);
                picks |= front;
                unsigned slo = infront ? mlo : 0u;
                unsigned shi = infront ? mhi : 0u;
                slo = dpp_or16(slo); shi = dpp_or16(shi);
                u64 sup = ((u64)wave_or_from_rows(shi) << 32) | wave_or_from_rows(slo);
                alive &= ~(front | sup);
                ++round;
            }

            int avail = POST_TOPN - K;
            int np = __popcll(picks);
            while (np > avail) {                       // truncate latest picks
                picks &= ~(1ULL << (63 - __clzll(picks)));
                --np;
            }
            int c = lane;
            bool ipick = ((picks >> c) & 1ULL) != 0;
            if (ipick) {
                int rank = __popcll(picks & ((1ULL << c) - 1ULL));
                int p = base + c;
                s_prevpicks[rb & 1][rank] = p;
                pg[K + rank] = p;                      // persist pick row
                float* o = out + ((size_t)b * POST_TOPN + K + rank) * 5;
                o[0] = (float)b; o[1] = mybox.x; o[2] = mybox.y; o[3] = mybox.z; o[4] = mybox.w;
            }
            // delta pipeline shift -- pure register selects (sd prefetched)
            u64 n1 = (ipick && havenext)  ? mysd1 : 0;
            u64 n2 = (ipick && havenext2) ? mysd2 : 0;
            cur1 = n1; cur2 = pend2; pend2 = n2;
            if (c == 0) {
                s_K = K + np;
                s_np[rb & 1] = np;
            }
            myrow = nrow; mysd1 = nsd1; mysd2 = nsd2; mybox = nbox;
        } else {
            // -- consume: preloads issued last iter (picks of rb-2) -> s_S --
            if (haveC) {
                u64 acc = 0;
#pragma unroll
                for (int t = 0; t < NPF; ++t) acc |= pf[t];
                acc &= amaskC;
                if (actC && acc) atomicOr(&s_S[colC], acc);
            }
            haveC = false;
            // -- issue: tails of picks of rb-1, consumed at iter rb+1 over
            //    cols [rb+2, rb1). 7 crew waves: len<=64 -> 7 stripes x seg0;
            //    len>64 -> {4 x stride-4 seg0, 3 x stride-3 seg1}. --
            int npp = s_np[pq];
            int lenn = rb1 - (rb + 2);
            int w = wv - 1;                   // 0..6
            if (npp > 0 && lenn > 0) {
                int s2, str, nstr;
                if (lenn > 64) { s2 = (w >= 4) ? 1 : 0; str = s2 ? (w - 4) : w; nstr = s2 ? 3 : 4; }
                else           { s2 = 0; str = w; nstr = 7; }
                const int* pp = s_prevpicks[pq];
                int ce = s2 * 64 + lane;
                bool act = (ce < lenn);
                actC = act;
                amaskC = act ? ~0ULL : 0ULL;
                colC = rb + 2 + (act ? ce : 0);
                int off = act ? (3 + ce) : 0;
                int last = npp - 1;
#pragma unroll
                for (int t = 0; t < NPF; ++t) {
                    int q = str + nstr * t;   // covers npp<=64 for nstr>=3
                    if (q > last) q = str;    // idempotent clamp (OR-safe)
                    pf[t] = bm[rowoff(pp[q]) + off];
                }
                haveC = true;
            }
        }
        WG_SYNC();
    }

    int K = s_K;
    bool finished = (K >= POST_TOPN) || (rb1 >= NBLK);
    if (finished) {
        for (int r = K + tid; r < POST_TOPN; r += 512) {
            float* o = out + ((size_t)b * POST_TOPN + r) * 5;
            o[0] = 0.0f; o[1] = 0.0f; o[2] = 0.0f; o[3] = 0.0f; o[4] = 0.0f;
        }
        if (tid == 0) done[b] = 1;
    } else {
        // persist running mask; picks of the last blocks get their tails
        // (cols >= rb1) OR'd by the NEXT stage's catch-up via picks_g.
        if (tid < NBLK) Sg[tid] = s_S[tid];
    }
    if (tid == 0) kcnt[b] = K;
}

// ---------------------------------------------------------------------------
// Fallback (round-2) NMS kernel — used only if ws_size can't hold the bitmap.
// ---------------------------------------------------------------------------
__global__ __launch_bounds__(1024) void nms_kernel(const float* __restrict__ boxes,
                                                   const u64* __restrict__ keys,
                                                   float* __restrict__ out,
                                                   int N) {
#pragma clang fp contract(off)
    __shared__ float4 kbox[POST_TOPN];
    __shared__ float kar[POST_TOPN];
    __shared__ float4 cbox[64];
    __shared__ float car_s[64];
    __shared__ int supp[64];
    __shared__ int s_cnt;

    int b = blockIdx.x;
    int tid = threadIdx.x;
    const u64* kb = keys + (size_t)b * SORTN;
    const float* bb = boxes + (size_t)b * N * 4;

    if (tid == 0) s_cnt = 0;
    __syncthreads();

    for (int start = 0; start < PRE_TOPN; start += 64) {
        int K = s_cnt;
        if (K >= POST_TOPN) break;
        int csize = min(64, PRE_TOPN - start);

        if (tid < 64) {
            int c = tid;
            if (c < csize) {
                u64 key = kb[start + c];
                int n = (int)(unsigned int)(key & 0xFFFFFFFFULL);
                const float* p = bb + (size_t)n * 4;
                float x1 = p[0], y1 = p[1], x2 = p[2], y2 = p[3];
                cbox[c] = make_float4(x1, y1, x2, y2);
                car_s[c] = ((x2 - x1) + 1.0f) * ((y2 - y1) + 1.0f);
            }
            supp[c] = 0;
        }
        __syncthreads();

        {
            int c = tid & 63;
            int sl = tid >> 6;
            if (c < csize) {
                float4 me = cbox[c];
                float ar = car_s[c];
                int flag = 0;
                for (int kk = sl; kk < K; kk += 16) {
                    float4 k0 = kbox[kk];
                    float a0 = kar[kk];
                    float xx1 = fmaxf(k0.x, me.x);
                    float yy1 = fmaxf(k0.y, me.y);
                    float xx2 = fminf(k0.z, me.z);
                    float yy2 = fminf(k0.w, me.w);
                    float w0 = fmaxf((xx2 - xx1) + 1.0f, 0.0f);
                    float h0 = fmaxf((yy2 - yy1) + 1.0f, 0.0f);
                    float inter0 = w0 * h0;
                    float iou0 = inter0 / ((a0 + ar) - inter0);
                    if (iou0 > 0.7f) { flag = 1; break; }
                }
                if (flag) supp[c] = 1;
            }
        }
        __syncthreads();

        if (tid < 64) {
            int c = tid;
            bool alive = (c < csize) && (supp[c] == 0);
            float4 me = cbox[c];
            float ar = car_s[c];
            int cnt = K;
            u64 m = __ballot(alive);
            while (m != 0 && cnt < POST_TOPN) {
                int i = __ffsll((unsigned long long)m) - 1;
                float ix1 = __shfl(me.x, i);
                float iy1 = __shfl(me.y, i);
                float ix2 = __shfl(me.z, i);
                float iy2 = __shfl(me.w, i);
                float iar = __shfl(ar, i);
                if (c == i) {
                    kbox[cnt] = me;
                    kar[cnt] = ar;
                    float* o = out + ((size_t)b * POST_TOPN + cnt) * 5;
                    o[0] = (float)b; o[1] = me.x; o[2] = me.y; o[3] = me.z; o[4] = me.w;
                }
                if (alive && c > i) {
                    float xx1 = fmaxf(ix1, me.x);
                    float yy1 = fmaxf(iy1, me.y);
                    float xx2 = fminf(ix2, me.z);
                    float yy2 = fminf(iy2, me.w);
                    float w = fmaxf((xx2 - xx1) + 1.0f, 0.0f);
                    float h = fmaxf((yy2 - yy1) + 1.0f, 0.0f);
                    float inter = w * h;
                    float iou = inter / ((iar + ar) - inter);
                    if (iou > 0.7f) alive = false;
                }
                cnt++;
                m = __ballot(alive);
                u64 clearmask = (2ULL << i) - 1ULL;
                m &= ~clearmask;
            }
            if (c == 0) s_cnt = cnt;
        }
        __syncthreads();
    }

    __syncthreads();
    int K = s_cnt;
    for (int r = K + tid; r < POST_TOPN; r += (int)blockDim.x) {
        float* o = out + ((size_t)b * POST_TOPN + r) * 5;
        o[0] = 0.0f; o[1] = 0.0f; o[2] = 0.0f; o[3] = 0.0f; o[4] = 0.0f;
    }
}

// ---------------------------------------------------------------------------
extern "C" void kernel_launch(void* const* d_in, const int* in_sizes, int n_in,
                              void* d_out, int out_size, void* d_ws, size_t ws_size,
                              hipStream_t stream) {
    const float* anchors = (const float*)d_in[0];
    const float* deltas  = (const float*)d_in[1];
    const float* scores  = (const float*)d_in[2];
    float* out = (float*)d_out;

    int N = in_sizes[0] / 4;           // 27380
    int B = in_sizes[2] / N;           // 8

    size_t off = 0;
    auto take = [&](size_t bytes) { size_t o = off; off = (off + bytes + 255) & ~(size_t)255; return o; };
    size_t boxesOff  = take((size_t)B * N * 4 * sizeof(float));
    size_t keysOff   = take((size_t)B * SORTN * sizeof(u64));
    size_t sboxOff   = take((size_t)B * PADN * sizeof(float4));
    size_t bitmapOff = take((size_t)B * TRI_WORDS * sizeof(u64));
    size_t diagOff   = take((size_t)B * PADN * sizeof(u64));
    size_t sd1Off    = take((size_t)B * PADN * sizeof(u64));
    size_t sd2Off    = take((size_t)B * PADN * sizeof(u64));
    size_t SgOff     = take((size_t)B * MASK_WORDS * sizeof(u64));
    size_t pgOff     = take((size_t)B * POST_TOPN * sizeof(int));
    size_t kcntOff   = take((size_t)B * sizeof(int));
    size_t doneOff   = take((size_t)B * sizeof(int));
    bool bitmap_path = (off <= ws_size);

    float* boxes = (float*)((char*)d_ws + boxesOff);
    u64*   keys  = (u64*)((char*)d_ws + keysOff);
    u64* diag    = bitmap_path ? (u64*)((char*)d_ws + diagOff)  : nullptr;
    u64* sd1     = bitmap_path ? (u64*)((char*)d_ws + sd1Off)   : nullptr;
    u64* sd2     = bitmap_path ? (u64*)((char*)d_ws + sd2Off)   : nullptr;
    u64* S_g     = bitmap_path ? (u64*)((char*)d_ws + SgOff)    : nullptr;
    int* pg      = bitmap_path ? (int*)((char*)d_ws + pgOff)    : nullptr;
    int* kcnt    = bitmap_path ? (int*)((char*)d_ws + kcntOff)  : nullptr;
    int* done    = bitmap_path ? (int*)((char*)d_ws + doneOff)  : nullptr;

    dim3 g1((unsigned)((SORTN + 255) / 256), (unsigned)B);
    decode_pack<<<g1, 256, 0, stream>>>(anchors, deltas, scores, boxes, keys, kcnt, done, N);

    // ---- sort: 2048-tiles local sort, then per level k a fused register-
    // orbit global kernel (all j >= 2048) + one LDS local merge (j <= 1024).
    int ntiles = B * NTILE;                       // 128 blocks
    bitonic_local_sort<<<ntiles, 256, 0, stream>>>(keys);
    {
        unsigned g1b = (unsigned)(B * (SORTN >> 1) / 256);
        bitonic_fused_global<1><<<g1b, 256, 0, stream>>>(keys);
        bitonic_local_merge<<<ntiles, 256, 0, stream>>>(keys, 4096);
        unsigned g2b = (unsigned)(B * (SORTN >> 2) / 256);
        bitonic_fused_global<2><<<g2b, 256, 0, stream>>>(keys);
        bitonic_local_merge<<<ntiles, 256, 0, stream>>>(keys, 8192);
        unsigned g3b = (unsigned)(B * (SORTN >> 3) / 256);
        bitonic_fused_global<3><<<g3b, 256, 0, stream>>>(keys);
        bitonic_local_merge<<<ntiles, 256, 0, stream>>>(keys, 16384);
        unsigned g4b = (unsigned)(B * (SORTN >> 4) / 256);
        bitonic_fused_global<4><<<g4b, 256, 0, stream>>>(keys);
        bitonic_local_merge<<<ntiles, 256, 0, stream>>>(keys, 32768);
    }

    if (bitmap_path) {
        float4* sbox = (float4*)((char*)d_ws + sboxOff);
        u64* bitmap  = (u64*)((char*)d_ws + bitmapOff);
        dim3 gg((unsigned)((PADN + 255) / 256), (unsigned)B);
        gather_sorted<<<gg, 256, 0, stream>>>(boxes, keys, sbox, N);

        // Progressive build/scan with per-batch done[] cutoff. Segments in
        // col-block units (even; widths <= 128 per the catch-up's 2-segment
        // mapping).
        const int seg[6] = {0, 48, 64, 88, 120, NBLK};
        for (int s = 0; s < 5; ++s) {
            int c0 = seg[s], c1 = seg[s + 1];
            int p0 = c0 / 2;
            int npair = (c1 - c0) / 2;
            unsigned gy = (unsigned)(((c1 / 2 - 1) >> 1) + 1);   // 256-row chunks
            dim3 gb((unsigned)npair, gy, (unsigned)B);
            build_bitmap<<<gb, 256, 0, stream>>>(sbox, bitmap, diag, sd1, sd2, done, p0);
            scan_nms<<<B, 512, 0, stream>>>(sbox, bitmap, diag, sd1, sd2, out, S_g, pg, kcnt, done, c0, c1);
        }
    } else {
        nms_kernel<<<B, 1024, 0, stream>>>(boxes, keys, out, N);
    }
}

// Round 12
// 241.704 us; speedup vs baseline: 1.0708x; 1.0708x over previous
//
#include <hip/hip_runtime.h>
#include <cmath>

typedef unsigned long long u64;

#define PRE_TOPN 12000
#define POST_TOPN 2000
#define SORTN 32768
#define TILE 2048              // local-sort tile
#define NTILE (SORTN / TILE)   // 16 tiles per batch
#define NBLK 188               // 64-bit column blocks covering 12032
#define PADN (NBLK * 64)       // 12032
// ROW-MAJOR triangular bitmap: row r stores words for col-blocks
// cb in [r/64, NBLK) contiguously at rowoff(r). Total words per batch:
#define TRI_WORDS (32 * (NBLK - 1) * NBLK + NBLK * 64)  // 1,137,024
#define MASK_WORDS 192         // 188 used, padded

// Light workgroup barrier: orders LDS (lgkmcnt) but lets global loads stay
// in flight across the barrier.
#define WG_SYNC() asm volatile("s_waitcnt lgkmcnt(0)\n\ts_barrier" ::: "memory")

__device__ __forceinline__ int rowoff(int r) {
    int rb = r >> 6;
    int q = r & 63;
    return r * NBLK - (32 * rb * (rb - 1) + q * rb);
}

// ---------------------------------------------------------------------------
// Kernel 1: decode boxes (exact fp32 op order, no FMA contraction, exp via
// double) and pack sort keys. key = (~score_bits)<<32 | idx.
// Also resets the per-batch NMS progress state (kcnt/done) for this launch.
// ---------------------------------------------------------------------------
__global__ void decode_pack(const float* __restrict__ anchors,
                            const float* __restrict__ deltas,
                            const float* __restrict__ scores,
                            float* __restrict__ boxes,
                            u64* __restrict__ keys,
                            int* __restrict__ kcnt,
                            int* __restrict__ done,
                            int N) {
#pragma clang fp contract(off)
    int n = blockIdx.x * blockDim.x + threadIdx.x;
    int b = blockIdx.y;
    if (kcnt != nullptr && blockIdx.x == 0 && threadIdx.x == 0) {
        kcnt[b] = 0;
        done[b] = 0;
    }
    if (n >= SORTN) return;
    u64* kb = keys + (size_t)b * SORTN;
    if (n < N) {
        float a0 = anchors[n * 4 + 0];
        float a1 = anchors[n * 4 + 1];
        float a2 = anchors[n * 4 + 2];
        float a3 = anchors[n * 4 + 3];
        float w = (a2 - a0) + 1.0f;
        float h = (a3 - a1) + 1.0f;
        float cx = a0 + 0.5f * w;
        float cy = a1 + 0.5f * h;
        const float* d = deltas + ((size_t)b * N + n) * 4;
        float dx = d[0], dy = d[1], dw = d[2], dh = d[3];
        float px = cx + w * dx;
        float py = cy + h * dy;
        float pw = (float)::exp((double)dw) * w;
        float ph = (float)::exp((double)dh) * h;
        float* bb = boxes + ((size_t)b * N + n) * 4;
        bb[0] = px - 0.5f * pw;
        bb[1] = py - 0.5f * ph;
        bb[2] = px + 0.5f * (pw - 2.0f);
        bb[3] = py + 0.5f * (ph - 2.0f);
        unsigned int sb = __float_as_uint(scores[(size_t)b * N + n]);
        kb[n] = ((u64)(~sb) << 32) | (u64)(unsigned int)n;
    } else {
        kb[n] = ~0ULL;
    }
}

// ---------------------------------------------------------------------------
// Hybrid bitonic sort: 2048-element tiles + register-orbit fused global steps.
// ---------------------------------------------------------------------------
__global__ __launch_bounds__(256) void bitonic_local_sort(u64* __restrict__ keys) {
    __shared__ u64 sk[TILE];
    int tile = blockIdx.x;
    u64* kb = keys + (size_t)tile * TILE;
    int base = (tile % NTILE) * TILE;
    for (int i = threadIdx.x; i < TILE; i += 256) sk[i] = kb[i];
    __syncthreads();
    for (int k = 2; k <= TILE; k <<= 1) {
        for (int j = k >> 1; j > 0; j >>= 1) {
            for (int t = threadIdx.x; t < TILE / 2; t += 256) {
                int i = ((t & ~(j - 1)) << 1) | (t & (j - 1));
                int ixj = i | j;
                u64 a = sk[i];
                u64 c = sk[ixj];
                bool up = (((base + i) & k) == 0);
                if ((a > c) == up) { sk[i] = c; sk[ixj] = a; }
            }
            __syncthreads();
        }
    }
    for (int i = threadIdx.x; i < TILE; i += 256) kb[i] = sk[i];
}

template<int G>
__global__ __launch_bounds__(256) void bitonic_fused_global(u64* __restrict__ keys) {
    const int K = TILE << G;
    const int M = 1 << G;
    int nbase = SORTN >> G;                  // base indices per batch
    int t = blockIdx.x * 256 + threadIdx.x;  // over B*nbase
    int b = t / nbase;
    int r = t % nbase;
    int low = r & (TILE - 1);
    int high = (r >> 11) << (11 + G);
    int base = high | low;
    u64* kb = keys + (size_t)b * SORTN;
    bool up = ((base & K) == 0);
    u64 e[M];
#pragma unroll
    for (int m = 0; m < M; ++m) e[m] = kb[base + (m << 11)];
#pragma unroll
    for (int s = G - 1; s >= 0; --s) {
        const int bit = 1 << s;
#pragma unroll
        for (int m = 0; m < M; ++m) {
            if (!(m & bit)) {
                u64 a = e[m], c = e[m | bit];
                if ((a > c) == up) { e[m] = c; e[m | bit] = a; }
            }
        }
    }
#pragma unroll
    for (int m = 0; m < M; ++m) kb[base + (m << 11)] = e[m];
}

__global__ __launch_bounds__(256) void bitonic_local_merge(u64* __restrict__ keys, int k) {
    __shared__ u64 sk[TILE];
    int tile = blockIdx.x;
    u64* kb = keys + (size_t)tile * TILE;
    int base = (tile % NTILE) * TILE;
    bool up = ((base & k) == 0);
    for (int i = threadIdx.x; i < TILE; i += 256) sk[i] = kb[i];
    __syncthreads();
    for (int j = TILE / 2; j > 0; j >>= 1) {
        for (int t = threadIdx.x; t < TILE / 2; t += 256) {
            int i = ((t & ~(j - 1)) << 1) | (t & (j - 1));
            int ixj = i | j;
            u64 a = sk[i];
            u64 c = sk[ixj];
            if ((a > c) == up) { sk[i] = c; sk[ixj] = a; }
        }
        __syncthreads();
    }
    for (int i = threadIdx.x; i < TILE; i += 256) kb[i] = sk[i];
}

// ---------------------------------------------------------------------------
// Gather sorted top-PADN boxes. Pad rows get far-away degenerate boxes.
// ---------------------------------------------------------------------------
__global__ void gather_sorted(const float* __restrict__ boxes,
                              const u64* __restrict__ keys,
                              float4* __restrict__ sbox, int N) {
    int r = blockIdx.x * 256 + threadIdx.x;
    int b = blockIdx.y;
    if (r >= PADN) return;
    float4 v;
    if (r < PRE_TOPN) {
        u64 key = keys[(size_t)b * SORTN + r];
        int n = (int)(unsigned)(key & 0xffffffffULL);
        v = ((const float4*)boxes)[(size_t)b * N + n];
    } else {
        v = make_float4(-4e8f, -4e8f, -4e8f, -4e8f);
    }
    sbox[(size_t)b * PADN + r] = v;
}

// ---------------------------------------------------------------------------
// Exact-f32 suppression predicate (bit-identical to the f64 reference test).
// ---------------------------------------------------------------------------
__device__ __forceinline__ void iou_bit(float4 me, float ar, float4 cj, float aj,
                                        int j, unsigned& lo, unsigned& hi, int& tie) {
#pragma clang fp contract(off)
    float xx1 = fmaxf(me.x, cj.x);
    float yy1 = fmaxf(me.y, cj.y);
    float xx2 = fminf(me.z, cj.z);
    float yy2 = fminf(me.w, cj.w);
    float w = fmaxf((xx2 - xx1) + 1.0f, 0.0f);
    float h = fmaxf((yy2 - yy1) + 1.0f, 0.0f);
    float inter = w * h;
    float un = (ar + aj) - inter;
    float t = __builtin_fmaf(-0.7f, un, inter);
    float u25 = un * 0x1p-25f;
    unsigned sup = (t > u25) ? 1u : 0u;
    tie |= (t == u25) ? 1 : 0;
    if (j < 32) lo |= sup << j;
    else        hi |= sup << (j - 32);
}

__device__ __attribute__((noinline)) u64 slow_word(float4 me, float ar,
                                                   const float4* cbox,
                                                   const float* carea) {
#pragma clang fp contract(off)
    const double MD = (double)0.7f + 0x1p-25;   // exact midpoint multiplier
    u64 word = 0;
    for (int j = 0; j < 64; ++j) {
        float4 cj = cbox[j];
        float aj = carea[j];
        float xx1 = fmaxf(me.x, cj.x);
        float yy1 = fmaxf(me.y, cj.y);
        float xx2 = fminf(me.z, cj.z);
        float yy2 = fminf(me.w, cj.w);
        float w = fmaxf((xx2 - xx1) + 1.0f, 0.0f);
        float h = fmaxf((yy2 - yy1) + 1.0f, 0.0f);
        float inter = w * h;
        float un = (ar + aj) - inter;
        bool sup = ((double)inter >= MD * (double)un);
        word |= ((u64)sup) << j;
    }
    return word;
}

// ---------------------------------------------------------------------------
// Build ROW-MAJOR suppression bitmap for col-block pairs [pair0, ...).
// Diagonal words -> diag[]; near-diagonal words (r, rb+1) -> sd1[] and
// (r, rb+2) -> sd2[] (contiguous), so the scan's wave0 has NO pick-dependent
// loads: its 2-deep delta pipeline reads prefetched sd registers.
// ---------------------------------------------------------------------------
__global__ __launch_bounds__(256) void build_bitmap(const float4* __restrict__ sbox,
                                                    u64* __restrict__ bitmap,
                                                    u64* __restrict__ diag,
                                                    u64* __restrict__ sd1,
                                                    u64* __restrict__ sd2,
                                                    const int* __restrict__ done,
                                                    int pair0) {
    int pair = pair0 + blockIdx.x;   // covers cbs 2*pair, 2*pair+1
    int chunk = blockIdx.y;          // 256-row chunk
    int b = blockIdx.z;
    if (done[b]) return;
    if (2 * chunk > pair) return;    // chunk's first row >= (2p+2)*64 -> empty
    int tid = threadIdx.x;
    int w = tid & 1;
    int cb = pair * 2 + w;
    int lim = (cb + 1) * 64;         // rows with words in column-block cb

    __shared__ float4 cbox[2][64];
    __shared__ float carea[2][64];
    const float4* sb = sbox + (size_t)b * PADN;
    if (tid < 128) {
        int which = tid >> 6, j = tid & 63;
        float4 c4 = sb[(pair * 2 + which) * 64 + j];
        cbox[which][j] = c4;
        carea[which][j] = ((c4.z - c4.x) + 1.0f) * ((c4.w - c4.y) + 1.0f);
    }
    int rl = tid >> 1;               // 0..127
    int r1 = chunk * 256 + rl;       // <= 46*256+127 = 11903 < PADN
    int r2 = r1 + 128;               // <= 12031 < PADN
    bool a1 = (r1 < lim);
    bool a2 = (r2 < lim);
    float4 me1 = sb[r1];
    float4 me2 = sb[r2];
    float ar1 = ((me1.z - me1.x) + 1.0f) * ((me1.w - me1.y) + 1.0f);
    float ar2 = ((me2.z - me2.x) + 1.0f) * ((me2.w - me2.y) + 1.0f);
    __syncthreads();

    u64* dgb = diag + (size_t)b * PADN;
    u64* sd1b = sd1 + (size_t)b * PADN;
    u64* sd2b = sd2 + (size_t)b * PADN;
    if (a1) {
        unsigned lo1 = 0, hi1 = 0;
        int tie1 = 0;
#pragma unroll
        for (int j = 0; j < 64; ++j) {
            iou_bit(me1, ar1, cbox[w][j], carea[w][j], j, lo1, hi1, tie1);
        }
        u64 w1 = ((u64)hi1 << 32) | lo1;
        if (__builtin_expect(tie1, 0)) w1 = slow_word(me1, ar1, cbox[w], carea[w]);
        int rbr = r1 >> 6;
        if (cb == rbr) {                             // diagonal block word
            w1 &= ~((2ULL << (r1 - cb * 64)) - 1ULL);
            dgb[r1] = w1;
        } else if (cb == rbr + 1) sd1b[r1] = w1;
        else if (cb == rbr + 2)   sd2b[r1] = w1;
        bitmap[(size_t)b * TRI_WORDS + rowoff(r1) + (cb - rbr)] = w1;
    }
    if (a2) {
        unsigned lo2 = 0, hi2 = 0;
        int tie2 = 0;
#pragma unroll
        for (int j = 0; j < 64; ++j) {
            iou_bit(me2, ar2, cbox[w][j], carea[w][j], j, lo2, hi2, tie2);
        }
        u64 w2 = ((u64)hi2 << 32) | lo2;
        if (__builtin_expect(tie2, 0)) w2 = slow_word(me2, ar2, cbox[w], carea[w]);
        int rbr = r2 >> 6;
        if (cb == rbr) {
            w2 &= ~((2ULL << (r2 - cb * 64)) - 1ULL);
            dgb[r2] = w2;
        } else if (cb == rbr + 1) sd1b[r2] = w2;
        else if (cb == rbr + 2)   sd2b[r2] = w2;
        bitmap[(size_t)b * TRI_WORDS + rowoff(r2) + (cb - rbr)] = w2;
    }
}

// ---------------------------------------------------------------------------
// DPP helpers: 16-lane OR-reduce, wave total via readlanes, and the
// canonical 64-lane inclusive prefix-OR scan.
// ---------------------------------------------------------------------------
__device__ __forceinline__ unsigned dpp_or16(unsigned v) {
    v |= (unsigned)__builtin_amdgcn_update_dpp(0, (int)v, 0xB1, 0xF, 0xF, true);   // quad_perm {1,0,3,2}
    v |= (unsigned)__builtin_amdgcn_update_dpp(0, (int)v, 0x4E, 0xF, 0xF, true);   // quad_perm {2,3,0,1}
    v |= (unsigned)__builtin_amdgcn_update_dpp(0, (int)v, 0x141, 0xF, 0xF, true);  // row_half_mirror
    v |= (unsigned)__builtin_amdgcn_update_dpp(0, (int)v, 0x140, 0xF, 0xF, true);  // row_mirror
    return v;
}

__device__ __forceinline__ unsigned wave_or_from_rows(unsigned rowred) {
    unsigned a = (unsigned)__builtin_amdgcn_readlane((int)rowred, 0) |
                 (unsigned)__builtin_amdgcn_readlane((int)rowred, 16);
    unsigned c = (unsigned)__builtin_amdgcn_readlane((int)rowred, 32) |
                 (unsigned)__builtin_amdgcn_readlane((int)rowred, 48);
    return a | c;
}

__device__ __forceinline__ unsigned wave_incl_prefix_or(unsigned v) {
    v |= (unsigned)__builtin_amdgcn_update_dpp(0, (int)v, 0x111, 0xF, 0xF, true);  // row_shr:1
    v |= (unsigned)__builtin_amdgcn_update_dpp(0, (int)v, 0x112, 0xF, 0xF, true);  // row_shr:2
    v |= (unsigned)__builtin_amdgcn_update_dpp(0, (int)v, 0x114, 0xF, 0xF, true);  // row_shr:4
    v |= (unsigned)__builtin_amdgcn_update_dpp(0, (int)v, 0x118, 0xF, 0xF, true);  // row_shr:8
    v |= (unsigned)__builtin_amdgcn_update_dpp(0, (int)v, 0x142, 0xA, 0xF, true);  // row_bcast:15 -> rows 1,3
    v |= (unsigned)__builtin_amdgcn_update_dpp(0, (int)v, 0x143, 0xC, 0xF, true);  // row_bcast:31 -> rows 2,3
    return v;
}

// ---------------------------------------------------------------------------
// Resumable scan, round-17 = round-15 (1024-thread, 15-crew, stride-5/NPF-16
// lag-2 pipeline -- the best-measured configuration, 45 us stage-1) with the
// one R16 change that is strictly beneficial: wave0's pick epilogue uses
// prefetched sd1/sd2 registers (word(p,rb+1), word(p,rb+2)) instead of
// pick-dependent bm loads, removing the last exposed latency on the critical
// wave. The 512-thread re-crew of R16 is REVERTED (it doubled crew load
// issue in the dominant early stages and regressed 45->62 us).
// Semantics identical to rounds 7-16.
// ---------------------------------------------------------------------------
__global__ __launch_bounds__(1024) void scan_nms(const float4* __restrict__ sbox,
                                                 const u64* __restrict__ bitmap,
                                                 const u64* __restrict__ diag,
                                                 const u64* __restrict__ sd1,
                                                 const u64* __restrict__ sd2,
                                                 float* __restrict__ out,
                                                 u64* __restrict__ S_g,
                                                 int* __restrict__ picks_g,
                                                 int* __restrict__ kcnt,
                                                 int* __restrict__ done,
                                                 int rb0, int rb1) {
    int b = blockIdx.x;
    if (done[b]) return;
    int tid = threadIdx.x;
    int lane = tid & 63;
    int wv = tid >> 6;                     // 0..15
    __shared__ u64 s_S[MASK_WORDS];        // 1.5 KB running suppression mask
    __shared__ int s_pp[POST_TOPN];        // 8 KB committed pick rows
    __shared__ int s_prevpicks[2][64];
    __shared__ int s_np[2];
    __shared__ int s_K;

    u64* Sg = S_g + (size_t)b * MASK_WORDS;
    int* pg = picks_g + (size_t)b * POST_TOPN;
    int K0 = kcnt[b];
    if (tid == 0) s_K = K0;
    if (tid < 2) s_np[tid] = 0;
    if (tid < MASK_WORDS) s_S[tid] = (tid < NBLK && rb0 > 0) ? Sg[tid] : 0ULL;
    for (int t = tid; t < K0; t += 1024) s_pp[t] = pg[t];
    WG_SYNC();

    const u64* bm = bitmap + (size_t)b * TRI_WORDS;
    const u64* dgb = diag + (size_t)b * PADN;
    const u64* sd1b = sd1 + (size_t)b * PADN;
    const u64* sd2b = sd2 + (size_t)b * PADN;
    const float4* sbb = sbox + (size_t)b * PADN;

    u64 myrow = 0, mysd1 = 0, mysd2 = 0;
    u64 cur1 = 0, cur2 = 0, pend2 = 0;     // wave0 2-deep delta pipeline
    u64 pf[16];                            // OR-crew preload regs (static idx)
#pragma unroll
    for (int t = 0; t < 16; ++t) pf[t] = 0;
    bool haveC = false, actC = false;
    u64 amaskC = 0;
    int colC = 0;
    float4 mybox = make_float4(0.f, 0.f, 0.f, 0.f);

    if (wv == 0) {
        // prologue diag/sd rows + box for rb0 (coalesced; overlaps catch-up)
        int r = rb0 * 64 + lane;
        myrow = dgb[r];
        mysd1 = sd1b[r];
        mysd2 = sd2b[r];
        mybox = sbb[r];
    } else if (rb0 > 0 && K0 > 0) {
        // ---- CATCH-UP: cols [rb0, rb1) x all K0 prior picks ----
        int width = rb1 - rb0;             // <= 128 by stage construction
        int nseg2 = (width + 63) >> 6;     // 1 or 2
        int w = wv - 1;                    // 0..14
        int s2, str, nstr;
        if (nseg2 == 2) { s2 = w & 1; str = w >> 1; nstr = (s2 == 0) ? 8 : 7; }
        else            { s2 = 0;     str = w;      nstr = 15; }
        int ce = s2 * 64 + lane;
        bool act = (ce < width);
        u64 amask = act ? ~0ULL : 0ULL;
        int cb = rb0 + ce;
        int cbc = act ? cb : rb0;
        u64 acc = 0;
        int last = K0 - 1;
        for (int q = str; q < K0; q += 8 * nstr) {
            int q0 = q;
            int q1 = q + nstr;     if (q1 > last) q1 = q0;
            int q2 = q + 2 * nstr; if (q2 > last) q2 = q0;
            int q3 = q + 3 * nstr; if (q3 > last) q3 = q0;
            int q4 = q + 4 * nstr; if (q4 > last) q4 = q0;
            int q5 = q + 5 * nstr; if (q5 > last) q5 = q0;
            int q6 = q + 6 * nstr; if (q6 > last) q6 = q0;
            int q7 = q + 7 * nstr; if (q7 > last) q7 = q0;
            int p0 = s_pp[q0], p1 = s_pp[q1], p2 = s_pp[q2], p3 = s_pp[q3];
            int p4 = s_pp[q4], p5 = s_pp[q5], p6 = s_pp[q6], p7 = s_pp[q7];
            u64 v0 = bm[rowoff(p0) + (cbc - (p0 >> 6))];
            u64 v1 = bm[rowoff(p1) + (cbc - (p1 >> 6))];
            u64 v2 = bm[rowoff(p2) + (cbc - (p2 >> 6))];
            u64 v3 = bm[rowoff(p3) + (cbc - (p3 >> 6))];
            u64 v4 = bm[rowoff(p4) + (cbc - (p4 >> 6))];
            u64 v5 = bm[rowoff(p5) + (cbc - (p5 >> 6))];
            u64 v6 = bm[rowoff(p6) + (cbc - (p6 >> 6))];
            u64 v7 = bm[rowoff(p7) + (cbc - (p7 >> 6))];
            acc |= ((v0 | v1) | (v2 | v3)) | ((v4 | v5) | (v6 | v7));
        }
        acc &= amask;
        if (act && acc) atomicOr(&s_S[cb], acc);
    }
    WG_SYNC();

    int rb = rb0;
    for (; rb < rb1; ++rb) {
        int K = s_K;                       // uniform (post-barrier)
        if (K >= POST_TOPN) break;
        int base = rb * 64;
        bool havenext = (rb + 1 < rb1);
        bool havenext2 = (rb + 2 < rb1);
        int pq = (rb + 1) & 1;             // parity of picks of rb-1

        if (wv == 0) {
            // early prefetch of next diag/sd rows + box (coalesced)
            u64 nrow = 0, nsd1 = 0, nsd2 = 0;
            float4 nbox = make_float4(0.f, 0.f, 0.f, 0.f);
            if (havenext) {
                int rn = (rb + 1) * 64 + lane;
                nrow = dgb[rn];
                nsd1 = sd1b[rn];
                nsd2 = sd2b[rn];
                nbox = sbb[rn];
            }
            // delta: picks(rb-1)@rb (cur1) | picks(rb-2)@rb (cur2)
            u64 dd = cur1 | cur2;
            unsigned rlo = dpp_or16((unsigned)(dd & 0xffffffffULL));
            unsigned rhi = dpp_or16((unsigned)(dd >> 32));
            u64 dtot = ((u64)wave_or_from_rows(rhi) << 32) | wave_or_from_rows(rlo);
            u64 t4 = s_S[rb] | dtot;
            if (rb == NBLK - 1) t4 |= 0xFFFFFFFF00000000ULL;   // pad rows >= 12000
            unsigned tlo = (unsigned)__builtin_amdgcn_readfirstlane((int)(t4 & 0xffffffffULL));
            unsigned thi = (unsigned)__builtin_amdgcn_readfirstlane((int)(t4 >> 32));
            u64 alive = ~(((u64)thi << 32) | tlo);
            unsigned mlo = (unsigned)(myrow & 0xffffffffULL);
            unsigned mhi = (unsigned)(myrow >> 32);

            // ---- frontier-batched greedy (exact serial-greedy pick set) ----
            u64 picks = 0;
            int round = 0;
            while (alive) {
                if (round >= 8) {
                    // serial fallback for pathological chain depth
                    u64 cur = alive;
                    while (cur) {
                        int i = (int)__builtin_ctzll(cur);
                        picks |= 1ULL << i;
                        unsigned rl = (unsigned)__builtin_amdgcn_readlane((int)mlo, i);
                        unsigned rh = (unsigned)__builtin_amdgcn_readlane((int)mhi, i);
                        u64 row = ((u64)rh << 32) | rl;
                        alive &= ~row;
                        cur = alive & ~((2ULL << i) - 1ULL);
                    }
                    break;
                }
                bool isal = ((alive >> lane) & 1ULL) != 0ULL;
                unsigned clo = isal ? mlo : 0u;
                unsigned chi = isal ? mhi : 0u;
                unsigned plo = wave_incl_prefix_or(clo);
                unsigned phi = wave_incl_prefix_or(chi);
                u64 pre = ((u64)phi << 32) | plo;
                bool infront = isal && (((pre >> lane) & 1ULL) == 0ULL);
                u64 front = __ballot(infront);
                picks |= front;
                unsigned slo = infront ? mlo : 0u;
                unsigned shi = infront ? mhi : 0u;
                slo = dpp_or16(slo); shi = dpp_or16(shi);
                u64 sup = ((u64)wave_or_from_rows(shi) << 32) | wave_or_from_rows(slo);
                alive &= ~(front | sup);
                ++round;
            }

            int avail = POST_TOPN - K;
            int np = __popcll(picks);
            while (np > avail) {                       // truncate latest picks
                picks &= ~(1ULL << (63 - __clzll(picks)));
                --np;
            }
            int c = lane;
            bool ipick = ((picks >> c) & 1ULL) != 0;
            if (ipick) {
                int rank = __popcll(picks & ((1ULL << c) - 1ULL));
                int p = base + c;
                s_prevpicks[rb & 1][rank] = p;
                pg[K + rank] = p;                      // persist pick row
                float* o = out + ((size_t)b * POST_TOPN + K + rank) * 5;
                o[0] = (float)b; o[1] = mybox.x; o[2] = mybox.y; o[3] = mybox.z; o[4] = mybox.w;
            }
            // delta pipeline shift -- pure register selects (sd prefetched)
            u64 n1 = (ipick && havenext)  ? mysd1 : 0;
            u64 n2 = (ipick && havenext2) ? mysd2 : 0;
            cur1 = n1; cur2 = pend2; pend2 = n2;
            if (c == 0) {
                s_K = K + np;
                s_np[rb & 1] = np;
            }
            myrow = nrow; mysd1 = nsd1; mysd2 = nsd2; mybox = nbox;
        } else {
            // -- consume: preloads issued last iter (picks of rb-2) -> s_S --
            if (haveC) {
                u64 acc = 0;
#pragma unroll
                for (int t = 0; t < 16; ++t) acc |= pf[t];
                acc &= amaskC;
                if (actC && acc) atomicOr(&s_S[colC], acc);
            }
            haveC = false;
            // -- issue: tails of picks of rb-1, consumed at iter rb+1 over
            //    cols [rb+2, rb1). wave w: col-seg (w-1)%3, stripe (w-1)/3. --
            int npp = s_np[pq];
            int lenn = rb1 - (rb + 2);
            int w = wv - 1;                   // 0..14
            int a3 = (w * 11) >> 5;           // w / 3
            int r3 = w - a3 * 3;              // w % 3
            if (npp > 0 && lenn > 0 && r3 * 64 < lenn) {
                const int* pp = s_prevpicks[pq];
                int ce = r3 * 64 + lane;
                bool act = (ce < lenn);
                actC = act;
                amaskC = act ? ~0ULL : 0ULL;
                colC = rb + 2 + (act ? ce : 0);
                int off = act ? (3 + ce) : 0;
                int last = npp - 1;
#pragma unroll
                for (int t = 0; t < 16; ++t) {
                    int q = a3 + 5 * t;       // stride-5 covers npp <= 64 (t<13)
                    if (q > last) q = a3;     // idempotent clamp (OR-safe)
                    pf[t] = bm[rowoff(pp[q]) + off];
                }
                haveC = true;
            }
        }
        WG_SYNC();
    }

    int K = s_K;
    bool finished = (K >= POST_TOPN) || (rb1 >= NBLK);
    if (finished) {
        for (int r = K + tid; r < POST_TOPN; r += 1024) {
            float* o = out + ((size_t)b * POST_TOPN + r) * 5;
            o[0] = 0.0f; o[1] = 0.0f; o[2] = 0.0f; o[3] = 0.0f; o[4] = 0.0f;
        }
        if (tid == 0) done[b] = 1;
    } else {
        // persist running mask; picks of the last blocks get their tails
        // (cols >= rb1) OR'd by the NEXT stage's catch-up via picks_g.
        if (tid < NBLK) Sg[tid] = s_S[tid];
    }
    if (tid == 0) kcnt[b] = K;
}

// ---------------------------------------------------------------------------
// Fallback (round-2) NMS kernel — used only if ws_size can't hold the bitmap.
// ---------------------------------------------------------------------------
__global__ __launch_bounds__(1024) void nms_kernel(const float* __restrict__ boxes,
                                                   const u64* __restrict__ keys,
                                                   float* __restrict__ out,
                                                   int N) {
#pragma clang fp contract(off)
    __shared__ float4 kbox[POST_TOPN];
    __shared__ float kar[POST_TOPN];
    __shared__ float4 cbox[64];
    __shared__ float car_s[64];
    __shared__ int supp[64];
    __shared__ int s_cnt;

    int b = blockIdx.x;
    int tid = threadIdx.x;
    const u64* kb = keys + (size_t)b * SORTN;
    const float* bb = boxes + (size_t)b * N * 4;

    if (tid == 0) s_cnt = 0;
    __syncthreads();

    for (int start = 0; start < PRE_TOPN; start += 64) {
        int K = s_cnt;
        if (K >= POST_TOPN) break;
        int csize = min(64, PRE_TOPN - start);

        if (tid < 64) {
            int c = tid;
            if (c < csize) {
                u64 key = kb[start + c];
                int n = (int)(unsigned int)(key & 0xFFFFFFFFULL);
                const float* p = bb + (size_t)n * 4;
                float x1 = p[0], y1 = p[1], x2 = p[2], y2 = p[3];
                cbox[c] = make_float4(x1, y1, x2, y2);
                car_s[c] = ((x2 - x1) + 1.0f) * ((y2 - y1) + 1.0f);
            }
            supp[c] = 0;
        }
        __syncthreads();

        {
            int c = tid & 63;
            int sl = tid >> 6;
            if (c < csize) {
                float4 me = cbox[c];
                float ar = car_s[c];
                int flag = 0;
                for (int kk = sl; kk < K; kk += 16) {
                    float4 k0 = kbox[kk];
                    float a0 = kar[kk];
                    float xx1 = fmaxf(k0.x, me.x);
                    float yy1 = fmaxf(k0.y, me.y);
                    float xx2 = fminf(k0.z, me.z);
                    float yy2 = fminf(k0.w, me.w);
                    float w0 = fmaxf((xx2 - xx1) + 1.0f, 0.0f);
                    float h0 = fmaxf((yy2 - yy1) + 1.0f, 0.0f);
                    float inter0 = w0 * h0;
                    float iou0 = inter0 / ((a0 + ar) - inter0);
                    if (iou0 > 0.7f) { flag = 1; break; }
                }
                if (flag) supp[c] = 1;
            }
        }
        __syncthreads();

        if (tid < 64) {
            int c = tid;
            bool alive = (c < csize) && (supp[c] == 0);
            float4 me = cbox[c];
            float ar = car_s[c];
            int cnt = K;
            u64 m = __ballot(alive);
            while (m != 0 && cnt < POST_TOPN) {
                int i = __ffsll((unsigned long long)m) - 1;
                float ix1 = __shfl(me.x, i);
                float iy1 = __shfl(me.y, i);
                float ix2 = __shfl(me.z, i);
                float iy2 = __shfl(me.w, i);
                float iar = __shfl(ar, i);
                if (c == i) {
                    kbox[cnt] = me;
                    kar[cnt] = ar;
                    float* o = out + ((size_t)b * POST_TOPN + cnt) * 5;
                    o[0] = (float)b; o[1] = me.x; o[2] = me.y; o[3] = me.z; o[4] = me.w;
                }
                if (alive && c > i) {
                    float xx1 = fmaxf(ix1, me.x);
                    float yy1 = fmaxf(iy1, me.y);
                    float xx2 = fminf(ix2, me.z);
                    float yy2 = fminf(iy2, me.w);
                    float w = fmaxf((xx2 - xx1) + 1.0f, 0.0f);
                    float h = fmaxf((yy2 - yy1) + 1.0f, 0.0f);
                    float inter = w * h;
                    float iou = inter / ((iar + ar) - inter);
                    if (iou > 0.7f) alive = false;
                }
                cnt++;
                m = __ballot(alive);
                u64 clearmask = (2ULL << i) - 1ULL;
                m &= ~clearmask;
            }
            if (c == 0) s_cnt = cnt;
        }
        __syncthreads();
    }

    __syncthreads();
    int K = s_cnt;
    for (int r = K + tid; r < POST_TOPN; r += (int)blockDim.x) {
        float* o = out + ((size_t)b * POST_TOPN + r) * 5;
        o[0] = 0.0f; o[1] = 0.0f; o[2] = 0.0f; o[3] = 0.0f; o[4] = 0.0f;
    }
}

// ---------------------------------------------------------------------------
extern "C" void kernel_launch(void* const* d_in, const int* in_sizes, int n_in,
                              void* d_out, int out_size, void* d_ws, size_t ws_size,
                              hipStream_t stream) {
    const float* anchors = (const float*)d_in[0];
    const float* deltas  = (const float*)d_in[1];
    const float* scores  = (const float*)d_in[2];
    float* out = (float*)d_out;

    int N = in_sizes[0] / 4;           // 27380
    int B = in_sizes[2] / N;           // 8

    size_t off = 0;
    auto take = [&](size_t bytes) { size_t o = off; off = (off + bytes + 255) & ~(size_t)255; return o; };
    size_t boxesOff  = take((size_t)B * N * 4 * sizeof(float));
    size_t keysOff   = take((size_t)B * SORTN * sizeof(u64));
    size_t sboxOff   = take((size_t)B * PADN * sizeof(float4));
    size_t bitmapOff = take((size_t)B * TRI_WORDS * sizeof(u64));
    size_t diagOff   = take((size_t)B * PADN * sizeof(u64));
    size_t sd1Off    = take((size_t)B * PADN * sizeof(u64));
    size_t sd2Off    = take((size_t)B * PADN * sizeof(u64));
    size_t SgOff     = take((size_t)B * MASK_WORDS * sizeof(u64));
    size_t pgOff     = take((size_t)B * POST_TOPN * sizeof(int));
    size_t kcntOff   = take((size_t)B * sizeof(int));
    size_t doneOff   = take((size_t)B * sizeof(int));
    bool bitmap_path = (off <= ws_size);

    float* boxes = (float*)((char*)d_ws + boxesOff);
    u64*   keys  = (u64*)((char*)d_ws + keysOff);
    u64* diag    = bitmap_path ? (u64*)((char*)d_ws + diagOff)  : nullptr;
    u64* sd1     = bitmap_path ? (u64*)((char*)d_ws + sd1Off)   : nullptr;
    u64* sd2     = bitmap_path ? (u64*)((char*)d_ws + sd2Off)   : nullptr;
    u64* S_g     = bitmap_path ? (u64*)((char*)d_ws + SgOff)    : nullptr;
    int* pg      = bitmap_path ? (int*)((char*)d_ws + pgOff)    : nullptr;
    int* kcnt    = bitmap_path ? (int*)((char*)d_ws + kcntOff)  : nullptr;
    int* done    = bitmap_path ? (int*)((char*)d_ws + doneOff)  : nullptr;

    dim3 g1((unsigned)((SORTN + 255) / 256), (unsigned)B);
    decode_pack<<<g1, 256, 0, stream>>>(anchors, deltas, scores, boxes, keys, kcnt, done, N);

    // ---- sort: 2048-tiles local sort, then per level k a fused register-
    // orbit global kernel (all j >= 2048) + one LDS local merge (j <= 1024).
    int ntiles = B * NTILE;                       // 128 blocks
    bitonic_local_sort<<<ntiles, 256, 0, stream>>>(keys);
    {
        unsigned g1b = (unsigned)(B * (SORTN >> 1) / 256);
        bitonic_fused_global<1><<<g1b, 256, 0, stream>>>(keys);
        bitonic_local_merge<<<ntiles, 256, 0, stream>>>(keys, 4096);
        unsigned g2b = (unsigned)(B * (SORTN >> 2) / 256);
        bitonic_fused_global<2><<<g2b, 256, 0, stream>>>(keys);
        bitonic_local_merge<<<ntiles, 256, 0, stream>>>(keys, 8192);
        unsigned g3b = (unsigned)(B * (SORTN >> 3) / 256);
        bitonic_fused_global<3><<<g3b, 256, 0, stream>>>(keys);
        bitonic_local_merge<<<ntiles, 256, 0, stream>>>(keys, 16384);
        unsigned g4b = (unsigned)(B * (SORTN >> 4) / 256);
        bitonic_fused_global<4><<<g4b, 256, 0, stream>>>(keys);
        bitonic_local_merge<<<ntiles, 256, 0, stream>>>(keys, 32768);
    }

    if (bitmap_path) {
        float4* sbox = (float4*)((char*)d_ws + sboxOff);
        u64* bitmap  = (u64*)((char*)d_ws + bitmapOff);
        dim3 gg((unsigned)((PADN + 255) / 256), (unsigned)B);
        gather_sorted<<<gg, 256, 0, stream>>>(boxes, keys, sbox, N);

        // Progressive build/scan with per-batch done[] cutoff. Segments in
        // col-block units (even; widths <= 128 per the catch-up's 2-segment
        // mapping).
        const int seg[6] = {0, 48, 64, 88, 120, NBLK};
        for (int s = 0; s < 5; ++s) {
            int c0 = seg[s], c1 = seg[s + 1];
            int p0 = c0 / 2;
            int npair = (c1 - c0) / 2;
            unsigned gy = (unsigned)(((c1 / 2 - 1) >> 1) + 1);   // 256-row chunks
            dim3 gb((unsigned)npair, gy, (unsigned)B);
            build_bitmap<<<gb, 256, 0, stream>>>(sbox, bitmap, diag, sd1, sd2, done, p0);
            scan_nms<<<B, 1024, 0, stream>>>(sbox, bitmap, diag, sd1, sd2, out, S_g, pg, kcnt, done, c0, c1);
        }
    } else {
        nms_kernel<<<B, 1024, 0, stream>>>(boxes, keys, out, N);
    }
}

// Round 13
// 237.417 us; speedup vs baseline: 1.0901x; 1.0181x over previous
//
#include <hip/hip_runtime.h>
#include <cmath>

typedef unsigned long long u64;

#define PRE_TOPN 12000
#define POST_TOPN 2000
#define SORTN 32768
#define TILE 2048              // local-sort tile
#define NTILE (SORTN / TILE)   // 16 tiles per batch
#define NBLK 188               // 64-bit column blocks covering 12032
#define PADN (NBLK * 64)       // 12032
// ROW-MAJOR triangular bitmap: row r stores words for col-blocks
// cb in [r/64, NBLK) contiguously at rowoff(r). Total words per batch:
#define TRI_WORDS (32 * (NBLK - 1) * NBLK + NBLK * 64)  // 1,137,024
#define MASK_WORDS 192         // 188 used, padded

// Light workgroup barrier: orders LDS (lgkmcnt) but lets global loads stay
// in flight across the barrier.
#define WG_SYNC() asm volatile("s_waitcnt lgkmcnt(0)\n\ts_barrier" ::: "memory")

__device__ __forceinline__ int rowoff(int r) {
    int rb = r >> 6;
    int q = r & 63;
    return r * NBLK - (32 * rb * (rb - 1) + q * rb);
}

// ---------------------------------------------------------------------------
// Kernel 1: decode boxes (exact fp32 op order, no FMA contraction, exp via
// double) and pack sort keys. key = (~score_bits)<<32 | idx.
// Also resets the per-batch NMS progress state (kcnt/done) for this launch.
// ---------------------------------------------------------------------------
__global__ void decode_pack(const float* __restrict__ anchors,
                            const float* __restrict__ deltas,
                            const float* __restrict__ scores,
                            float* __restrict__ boxes,
                            u64* __restrict__ keys,
                            int* __restrict__ kcnt,
                            int* __restrict__ done,
                            int N) {
#pragma clang fp contract(off)
    int n = blockIdx.x * blockDim.x + threadIdx.x;
    int b = blockIdx.y;
    if (kcnt != nullptr && blockIdx.x == 0 && threadIdx.x == 0) {
        kcnt[b] = 0;
        done[b] = 0;
    }
    if (n >= SORTN) return;
    u64* kb = keys + (size_t)b * SORTN;
    if (n < N) {
        float a0 = anchors[n * 4 + 0];
        float a1 = anchors[n * 4 + 1];
        float a2 = anchors[n * 4 + 2];
        float a3 = anchors[n * 4 + 3];
        float w = (a2 - a0) + 1.0f;
        float h = (a3 - a1) + 1.0f;
        float cx = a0 + 0.5f * w;
        float cy = a1 + 0.5f * h;
        const float* d = deltas + ((size_t)b * N + n) * 4;
        float dx = d[0], dy = d[1], dw = d[2], dh = d[3];
        float px = cx + w * dx;
        float py = cy + h * dy;
        float pw = (float)::exp((double)dw) * w;
        float ph = (float)::exp((double)dh) * h;
        float* bb = boxes + ((size_t)b * N + n) * 4;
        bb[0] = px - 0.5f * pw;
        bb[1] = py - 0.5f * ph;
        bb[2] = px + 0.5f * (pw - 2.0f);
        bb[3] = py + 0.5f * (ph - 2.0f);
        unsigned int sb = __float_as_uint(scores[(size_t)b * N + n]);
        kb[n] = ((u64)(~sb) << 32) | (u64)(unsigned int)n;
    } else {
        kb[n] = ~0ULL;
    }
}

// ---------------------------------------------------------------------------
// Hybrid bitonic sort: 2048-element tiles + register-orbit fused global steps.
// ---------------------------------------------------------------------------
__global__ __launch_bounds__(256) void bitonic_local_sort(u64* __restrict__ keys) {
    __shared__ u64 sk[TILE];
    int tile = blockIdx.x;
    u64* kb = keys + (size_t)tile * TILE;
    int base = (tile % NTILE) * TILE;
    for (int i = threadIdx.x; i < TILE; i += 256) sk[i] = kb[i];
    __syncthreads();
    for (int k = 2; k <= TILE; k <<= 1) {
        for (int j = k >> 1; j > 0; j >>= 1) {
            for (int t = threadIdx.x; t < TILE / 2; t += 256) {
                int i = ((t & ~(j - 1)) << 1) | (t & (j - 1));
                int ixj = i | j;
                u64 a = sk[i];
                u64 c = sk[ixj];
                bool up = (((base + i) & k) == 0);
                if ((a > c) == up) { sk[i] = c; sk[ixj] = a; }
            }
            __syncthreads();
        }
    }
    for (int i = threadIdx.x; i < TILE; i += 256) kb[i] = sk[i];
}

template<int G>
__global__ __launch_bounds__(256) void bitonic_fused_global(u64* __restrict__ keys) {
    const int K = TILE << G;
    const int M = 1 << G;
    int nbase = SORTN >> G;                  // base indices per batch
    int t = blockIdx.x * 256 + threadIdx.x;  // over B*nbase
    int b = t / nbase;
    int r = t % nbase;
    int low = r & (TILE - 1);
    int high = (r >> 11) << (11 + G);
    int base = high | low;
    u64* kb = keys + (size_t)b * SORTN;
    bool up = ((base & K) == 0);
    u64 e[M];
#pragma unroll
    for (int m = 0; m < M; ++m) e[m] = kb[base + (m << 11)];
#pragma unroll
    for (int s = G - 1; s >= 0; --s) {
        const int bit = 1 << s;
#pragma unroll
        for (int m = 0; m < M; ++m) {
            if (!(m & bit)) {
                u64 a = e[m], c = e[m | bit];
                if ((a > c) == up) { e[m] = c; e[m | bit] = a; }
            }
        }
    }
#pragma unroll
    for (int m = 0; m < M; ++m) kb[base + (m << 11)] = e[m];
}

__global__ __launch_bounds__(256) void bitonic_local_merge(u64* __restrict__ keys, int k) {
    __shared__ u64 sk[TILE];
    int tile = blockIdx.x;
    u64* kb = keys + (size_t)tile * TILE;
    int base = (tile % NTILE) * TILE;
    bool up = ((base & k) == 0);
    for (int i = threadIdx.x; i < TILE; i += 256) sk[i] = kb[i];
    __syncthreads();
    for (int j = TILE / 2; j > 0; j >>= 1) {
        for (int t = threadIdx.x; t < TILE / 2; t += 256) {
            int i = ((t & ~(j - 1)) << 1) | (t & (j - 1));
            int ixj = i | j;
            u64 a = sk[i];
            u64 c = sk[ixj];
            if ((a > c) == up) { sk[i] = c; sk[ixj] = a; }
        }
        __syncthreads();
    }
    for (int i = threadIdx.x; i < TILE; i += 256) kb[i] = sk[i];
}

// ---------------------------------------------------------------------------
// Gather sorted top-PADN boxes. Pad rows get far-away degenerate boxes.
// ---------------------------------------------------------------------------
__global__ void gather_sorted(const float* __restrict__ boxes,
                              const u64* __restrict__ keys,
                              float4* __restrict__ sbox, int N) {
    int r = blockIdx.x * 256 + threadIdx.x;
    int b = blockIdx.y;
    if (r >= PADN) return;
    float4 v;
    if (r < PRE_TOPN) {
        u64 key = keys[(size_t)b * SORTN + r];
        int n = (int)(unsigned)(key & 0xffffffffULL);
        v = ((const float4*)boxes)[(size_t)b * N + n];
    } else {
        v = make_float4(-4e8f, -4e8f, -4e8f, -4e8f);
    }
    sbox[(size_t)b * PADN + r] = v;
}

// ---------------------------------------------------------------------------
// Exact-f32 suppression predicate (bit-identical to the f64 reference test).
// ---------------------------------------------------------------------------
__device__ __forceinline__ void iou_bit(float4 me, float ar, float4 cj, float aj,
                                        int j, unsigned& lo, unsigned& hi, int& tie) {
#pragma clang fp contract(off)
    float xx1 = fmaxf(me.x, cj.x);
    float yy1 = fmaxf(me.y, cj.y);
    float xx2 = fminf(me.z, cj.z);
    float yy2 = fminf(me.w, cj.w);
    float w = fmaxf((xx2 - xx1) + 1.0f, 0.0f);
    float h = fmaxf((yy2 - yy1) + 1.0f, 0.0f);
    float inter = w * h;
    float un = (ar + aj) - inter;
    float t = __builtin_fmaf(-0.7f, un, inter);
    float u25 = un * 0x1p-25f;
    unsigned sup = (t > u25) ? 1u : 0u;
    tie |= (t == u25) ? 1 : 0;
    if (j < 32) lo |= sup << j;
    else        hi |= sup << (j - 32);
}

__device__ __attribute__((noinline)) u64 slow_word(float4 me, float ar,
                                                   const float4* cbox,
                                                   const float* carea) {
#pragma clang fp contract(off)
    const double MD = (double)0.7f + 0x1p-25;   // exact midpoint multiplier
    u64 word = 0;
    for (int j = 0; j < 64; ++j) {
        float4 cj = cbox[j];
        float aj = carea[j];
        float xx1 = fmaxf(me.x, cj.x);
        float yy1 = fmaxf(me.y, cj.y);
        float xx2 = fminf(me.z, cj.z);
        float yy2 = fminf(me.w, cj.w);
        float w = fmaxf((xx2 - xx1) + 1.0f, 0.0f);
        float h = fmaxf((yy2 - yy1) + 1.0f, 0.0f);
        float inter = w * h;
        float un = (ar + aj) - inter;
        bool sup = ((double)inter >= MD * (double)un);
        word |= ((u64)sup) << j;
    }
    return word;
}

// ---------------------------------------------------------------------------
// Build ROW-MAJOR suppression bitmap for col-block pairs [pair0, ...).
// Diagonal words -> diag[]; near-diagonal words (r, rb+1) -> sd1[] and
// (r, rb+2) -> sd2[] (contiguous), so the scan's wave0 has NO pick-dependent
// loads: its 2-deep delta pipeline reads prefetched sd registers.
// ---------------------------------------------------------------------------
__global__ __launch_bounds__(256) void build_bitmap(const float4* __restrict__ sbox,
                                                    u64* __restrict__ bitmap,
                                                    u64* __restrict__ diag,
                                                    u64* __restrict__ sd1,
                                                    u64* __restrict__ sd2,
                                                    const int* __restrict__ done,
                                                    int pair0) {
    int pair = pair0 + blockIdx.x;   // covers cbs 2*pair, 2*pair+1
    int chunk = blockIdx.y;          // 256-row chunk
    int b = blockIdx.z;
    if (done[b]) return;
    if (2 * chunk > pair) return;    // chunk's first row >= (2p+2)*64 -> empty
    int tid = threadIdx.x;
    int w = tid & 1;
    int cb = pair * 2 + w;
    int lim = (cb + 1) * 64;         // rows with words in column-block cb

    __shared__ float4 cbox[2][64];
    __shared__ float carea[2][64];
    const float4* sb = sbox + (size_t)b * PADN;
    if (tid < 128) {
        int which = tid >> 6, j = tid & 63;
        float4 c4 = sb[(pair * 2 + which) * 64 + j];
        cbox[which][j] = c4;
        carea[which][j] = ((c4.z - c4.x) + 1.0f) * ((c4.w - c4.y) + 1.0f);
    }
    int rl = tid >> 1;               // 0..127
    int r1 = chunk * 256 + rl;       // <= 46*256+127 = 11903 < PADN
    int r2 = r1 + 128;               // <= 12031 < PADN
    bool a1 = (r1 < lim);
    bool a2 = (r2 < lim);
    float4 me1 = sb[r1];
    float4 me2 = sb[r2];
    float ar1 = ((me1.z - me1.x) + 1.0f) * ((me1.w - me1.y) + 1.0f);
    float ar2 = ((me2.z - me2.x) + 1.0f) * ((me2.w - me2.y) + 1.0f);
    __syncthreads();

    u64* dgb = diag + (size_t)b * PADN;
    u64* sd1b = sd1 + (size_t)b * PADN;
    u64* sd2b = sd2 + (size_t)b * PADN;
    if (a1) {
        unsigned lo1 = 0, hi1 = 0;
        int tie1 = 0;
#pragma unroll
        for (int j = 0; j < 64; ++j) {
            iou_bit(me1, ar1, cbox[w][j], carea[w][j], j, lo1, hi1, tie1);
        }
        u64 w1 = ((u64)hi1 << 32) | lo1;
        if (__builtin_expect(tie1, 0)) w1 = slow_word(me1, ar1, cbox[w], carea[w]);
        int rbr = r1 >> 6;
        if (cb == rbr) {                             // diagonal block word
            w1 &= ~((2ULL << (r1 - cb * 64)) - 1ULL);
            dgb[r1] = w1;
        } else if (cb == rbr + 1) sd1b[r1] = w1;
        else if (cb == rbr + 2)   sd2b[r1] = w1;
        bitmap[(size_t)b * TRI_WORDS + rowoff(r1) + (cb - rbr)] = w1;
    }
    if (a2) {
        unsigned lo2 = 0, hi2 = 0;
        int tie2 = 0;
#pragma unroll
        for (int j = 0; j < 64; ++j) {
            iou_bit(me2, ar2, cbox[w][j], carea[w][j], j, lo2, hi2, tie2);
        }
        u64 w2 = ((u64)hi2 << 32) | lo2;
        if (__builtin_expect(tie2, 0)) w2 = slow_word(me2, ar2, cbox[w], carea[w]);
        int rbr = r2 >> 6;
        if (cb == rbr) {
            w2 &= ~((2ULL << (r2 - cb * 64)) - 1ULL);
            dgb[r2] = w2;
        } else if (cb == rbr + 1) sd1b[r2] = w2;
        else if (cb == rbr + 2)   sd2b[r2] = w2;
        bitmap[(size_t)b * TRI_WORDS + rowoff(r2) + (cb - rbr)] = w2;
    }
}

// ---------------------------------------------------------------------------
// DPP helpers: 16-lane OR-reduce, wave total via readlanes, and the
// canonical 64-lane inclusive prefix-OR scan.
// ---------------------------------------------------------------------------
__device__ __forceinline__ unsigned dpp_or16(unsigned v) {
    v |= (unsigned)__builtin_amdgcn_update_dpp(0, (int)v, 0xB1, 0xF, 0xF, true);   // quad_perm {1,0,3,2}
    v |= (unsigned)__builtin_amdgcn_update_dpp(0, (int)v, 0x4E, 0xF, 0xF, true);   // quad_perm {2,3,0,1}
    v |= (unsigned)__builtin_amdgcn_update_dpp(0, (int)v, 0x141, 0xF, 0xF, true);  // row_half_mirror
    v |= (unsigned)__builtin_amdgcn_update_dpp(0, (int)v, 0x140, 0xF, 0xF, true);  // row_mirror
    return v;
}

__device__ __forceinline__ unsigned wave_or_from_rows(unsigned rowred) {
    unsigned a = (unsigned)__builtin_amdgcn_readlane((int)rowred, 0) |
                 (unsigned)__builtin_amdgcn_readlane((int)rowred, 16);
    unsigned c = (unsigned)__builtin_amdgcn_readlane((int)rowred, 32) |
                 (unsigned)__builtin_amdgcn_readlane((int)rowred, 48);
    return a | c;
}

__device__ __forceinline__ unsigned wave_incl_prefix_or(unsigned v) {
    v |= (unsigned)__builtin_amdgcn_update_dpp(0, (int)v, 0x111, 0xF, 0xF, true);  // row_shr:1
    v |= (unsigned)__builtin_amdgcn_update_dpp(0, (int)v, 0x112, 0xF, 0xF, true);  // row_shr:2
    v |= (unsigned)__builtin_amdgcn_update_dpp(0, (int)v, 0x114, 0xF, 0xF, true);  // row_shr:4
    v |= (unsigned)__builtin_amdgcn_update_dpp(0, (int)v, 0x118, 0xF, 0xF, true);  // row_shr:8
    v |= (unsigned)__builtin_amdgcn_update_dpp(0, (int)v, 0x142, 0xA, 0xF, true);  // row_bcast:15 -> rows 1,3
    v |= (unsigned)__builtin_amdgcn_update_dpp(0, (int)v, 0x143, 0xC, 0xF, true);  // row_bcast:31 -> rows 2,3
    return v;
}

// ---------------------------------------------------------------------------
// Resumable scan, round-18 = round-17 structure + two contention fixes:
//  (a) wave0 runs at s_setprio(1) for the whole kernel (T5 role-split: the
//      critical serial wave preempts crew issue on its shared SIMD; crew
//      has >= 1 iteration of slack so stolen slots are free);
//  (b) pick lists store PRECOMPUTED bases rowoff(p)-(p>>6) so every crew /
//      catch-up load address is one add (bm[base+col]) instead of an 8-op
//      rowoff() chain -- shrinking the crew issue stream that competes with
//      wave0's latency-bound DPP chain.
// Semantics identical to rounds 7-17.
// ---------------------------------------------------------------------------
__global__ __launch_bounds__(1024) void scan_nms(const float4* __restrict__ sbox,
                                                 const u64* __restrict__ bitmap,
                                                 const u64* __restrict__ diag,
                                                 const u64* __restrict__ sd1,
                                                 const u64* __restrict__ sd2,
                                                 float* __restrict__ out,
                                                 u64* __restrict__ S_g,
                                                 int* __restrict__ picks_g,
                                                 int* __restrict__ kcnt,
                                                 int* __restrict__ done,
                                                 int rb0, int rb1) {
    int b = blockIdx.x;
    if (done[b]) return;
    int tid = threadIdx.x;
    int lane = tid & 63;
    int wv = tid >> 6;                     // 0..15
    __shared__ u64 s_S[MASK_WORDS];        // 1.5 KB running suppression mask
    __shared__ int s_pp[POST_TOPN];        // 8 KB committed pick BASES
    __shared__ int s_prevpicks[2][64];     // pick BASES (rowoff(p)-(p>>6))
    __shared__ int s_np[2];
    __shared__ int s_K;

    if (wv == 0) __builtin_amdgcn_s_setprio(1);   // critical wave priority

    u64* Sg = S_g + (size_t)b * MASK_WORDS;
    int* pg = picks_g + (size_t)b * POST_TOPN;
    int K0 = kcnt[b];
    if (tid == 0) s_K = K0;
    if (tid < 2) s_np[tid] = 0;
    if (tid < MASK_WORDS) s_S[tid] = (tid < NBLK && rb0 > 0) ? Sg[tid] : 0ULL;
    for (int t = tid; t < K0; t += 1024) s_pp[t] = pg[t];
    WG_SYNC();

    const u64* bm = bitmap + (size_t)b * TRI_WORDS;
    const u64* dgb = diag + (size_t)b * PADN;
    const u64* sd1b = sd1 + (size_t)b * PADN;
    const u64* sd2b = sd2 + (size_t)b * PADN;
    const float4* sbb = sbox + (size_t)b * PADN;

    u64 myrow = 0, mysd1 = 0, mysd2 = 0;
    u64 cur1 = 0, cur2 = 0, pend2 = 0;     // wave0 2-deep delta pipeline
    u64 pf[16];                            // OR-crew preload regs (static idx)
#pragma unroll
    for (int t = 0; t < 16; ++t) pf[t] = 0;
    bool haveC = false, actC = false;
    u64 amaskC = 0;
    int colC = 0;
    float4 mybox = make_float4(0.f, 0.f, 0.f, 0.f);

    if (wv == 0) {
        // prologue diag/sd rows + box for rb0 (coalesced; overlaps catch-up)
        int r = rb0 * 64 + lane;
        myrow = dgb[r];
        mysd1 = sd1b[r];
        mysd2 = sd2b[r];
        mybox = sbb[r];
    } else if (rb0 > 0 && K0 > 0) {
        // ---- CATCH-UP: cols [rb0, rb1) x all K0 prior picks (bases) ----
        int width = rb1 - rb0;             // <= 128 by stage construction
        int nseg2 = (width + 63) >> 6;     // 1 or 2
        int w = wv - 1;                    // 0..14
        int s2, str, nstr;
        if (nseg2 == 2) { s2 = w & 1; str = w >> 1; nstr = (s2 == 0) ? 8 : 7; }
        else            { s2 = 0;     str = w;      nstr = 15; }
        int ce = s2 * 64 + lane;
        bool act = (ce < width);
        u64 amask = act ? ~0ULL : 0ULL;
        int cb = rb0 + ce;
        int cbc = act ? cb : rb0;
        u64 acc = 0;
        int last = K0 - 1;
        for (int q = str; q < K0; q += 8 * nstr) {
            int q0 = q;
            int q1 = q + nstr;     if (q1 > last) q1 = q0;
            int q2 = q + 2 * nstr; if (q2 > last) q2 = q0;
            int q3 = q + 3 * nstr; if (q3 > last) q3 = q0;
            int q4 = q + 4 * nstr; if (q4 > last) q4 = q0;
            int q5 = q + 5 * nstr; if (q5 > last) q5 = q0;
            int q6 = q + 6 * nstr; if (q6 > last) q6 = q0;
            int q7 = q + 7 * nstr; if (q7 > last) q7 = q0;
            int p0 = s_pp[q0], p1 = s_pp[q1], p2 = s_pp[q2], p3 = s_pp[q3];
            int p4 = s_pp[q4], p5 = s_pp[q5], p6 = s_pp[q6], p7 = s_pp[q7];
            u64 v0 = bm[p0 + cbc];
            u64 v1 = bm[p1 + cbc];
            u64 v2 = bm[p2 + cbc];
            u64 v3 = bm[p3 + cbc];
            u64 v4 = bm[p4 + cbc];
            u64 v5 = bm[p5 + cbc];
            u64 v6 = bm[p6 + cbc];
            u64 v7 = bm[p7 + cbc];
            acc |= ((v0 | v1) | (v2 | v3)) | ((v4 | v5) | (v6 | v7));
        }
        acc &= amask;
        if (act && acc) atomicOr(&s_S[cb], acc);
    }
    WG_SYNC();

    int rb = rb0;
    for (; rb < rb1; ++rb) {
        int K = s_K;                       // uniform (post-barrier)
        if (K >= POST_TOPN) break;
        int base = rb * 64;
        bool havenext = (rb + 1 < rb1);
        bool havenext2 = (rb + 2 < rb1);
        int pq = (rb + 1) & 1;             // parity of picks of rb-1

        if (wv == 0) {
            // early prefetch of next diag/sd rows + box (coalesced)
            u64 nrow = 0, nsd1 = 0, nsd2 = 0;
            float4 nbox = make_float4(0.f, 0.f, 0.f, 0.f);
            if (havenext) {
                int rn = (rb + 1) * 64 + lane;
                nrow = dgb[rn];
                nsd1 = sd1b[rn];
                nsd2 = sd2b[rn];
                nbox = sbb[rn];
            }
            // delta: picks(rb-1)@rb (cur1) | picks(rb-2)@rb (cur2)
            u64 dd = cur1 | cur2;
            unsigned rlo = dpp_or16((unsigned)(dd & 0xffffffffULL));
            unsigned rhi = dpp_or16((unsigned)(dd >> 32));
            u64 dtot = ((u64)wave_or_from_rows(rhi) << 32) | wave_or_from_rows(rlo);
            u64 t4 = s_S[rb] | dtot;
            if (rb == NBLK - 1) t4 |= 0xFFFFFFFF00000000ULL;   // pad rows >= 12000
            unsigned tlo = (unsigned)__builtin_amdgcn_readfirstlane((int)(t4 & 0xffffffffULL));
            unsigned thi = (unsigned)__builtin_amdgcn_readfirstlane((int)(t4 >> 32));
            u64 alive = ~(((u64)thi << 32) | tlo);
            unsigned mlo = (unsigned)(myrow & 0xffffffffULL);
            unsigned mhi = (unsigned)(myrow >> 32);

            // ---- frontier-batched greedy (exact serial-greedy pick set) ----
            u64 picks = 0;
            int round = 0;
            while (alive) {
                if (round >= 8) {
                    // serial fallback for pathological chain depth
                    u64 cur = alive;
                    while (cur) {
                        int i = (int)__builtin_ctzll(cur);
                        picks |= 1ULL << i;
                        unsigned rl = (unsigned)__builtin_amdgcn_readlane((int)mlo, i);
                        unsigned rh = (unsigned)__builtin_amdgcn_readlane((int)mhi, i);
                        u64 row = ((u64)rh << 32) | rl;
                        alive &= ~row;
                        cur = alive & ~((2ULL << i) - 1ULL);
                    }
                    break;
                }
                bool isal = ((alive >> lane) & 1ULL) != 0ULL;
                unsigned clo = isal ? mlo : 0u;
                unsigned chi = isal ? mhi : 0u;
                unsigned plo = wave_incl_prefix_or(clo);
                unsigned phi = wave_incl_prefix_or(chi);
                u64 pre = ((u64)phi << 32) | plo;
                bool infront = isal && (((pre >> lane) & 1ULL) == 0ULL);
                u64 front = __ballot(infront);
                picks |= front;
                unsigned slo = infront ? mlo : 0u;
                unsigned shi = infront ? mhi : 0u;
                slo = dpp_or16(slo); shi = dpp_or16(shi);
                u64 sup = ((u64)wave_or_from_rows(shi) << 32) | wave_or_from_rows(slo);
                alive &= ~(front | sup);
                ++round;
            }

            int avail = POST_TOPN - K;
            int np = __popcll(picks);
            while (np > avail) {                       // truncate latest picks
                picks &= ~(1ULL << (63 - __clzll(picks)));
                --np;
            }
            int c = lane;
            bool ipick = ((picks >> c) & 1ULL) != 0;
            if (ipick) {
                int rank = __popcll(picks & ((1ULL << c) - 1ULL));
                int p = base + c;
                int pbase = rowoff(p) - rb;            // p>>6 == rb
                s_prevpicks[rb & 1][rank] = pbase;
                pg[K + rank] = pbase;                  // persist pick base
                float* o = out + ((size_t)b * POST_TOPN + K + rank) * 5;
                o[0] = (float)b; o[1] = mybox.x; o[2] = mybox.y; o[3] = mybox.z; o[4] = mybox.w;
            }
            // delta pipeline shift -- pure register selects (sd prefetched)
            u64 n1 = (ipick && havenext)  ? mysd1 : 0;
            u64 n2 = (ipick && havenext2) ? mysd2 : 0;
            cur1 = n1; cur2 = pend2; pend2 = n2;
            if (c == 0) {
                s_K = K + np;
                s_np[rb & 1] = np;
            }
            myrow = nrow; mysd1 = nsd1; mysd2 = nsd2; mybox = nbox;
        } else {
            // -- consume: preloads issued last iter (picks of rb-2) -> s_S --
            if (haveC) {
                u64 acc = 0;
#pragma unroll
                for (int t = 0; t < 16; ++t) acc |= pf[t];
                acc &= amaskC;
                if (actC && acc) atomicOr(&s_S[colC], acc);
            }
            haveC = false;
            // -- issue: tails of picks of rb-1 (bases), consumed at iter rb+1
            //    over cols [rb+2, rb1). wave w: col-seg (w-1)%3, stripe (w-1)/3.
            int npp = s_np[pq];
            int lenn = rb1 - (rb + 2);
            int w = wv - 1;                   // 0..14
            int a3 = (w * 11) >> 5;           // w / 3
            int r3 = w - a3 * 3;              // w % 3
            if (npp > 0 && lenn > 0 && r3 * 64 < lenn) {
                const int* pp = s_prevpicks[pq];
                int ce = r3 * 64 + lane;
                bool act = (ce < lenn);
                actC = act;
                amaskC = act ? ~0ULL : 0ULL;
                colC = rb + 2 + (act ? ce : 0);
                int col = colC;               // bm[base + col]
                int last = npp - 1;
#pragma unroll
                for (int t = 0; t < 16; ++t) {
                    int q = a3 + 5 * t;       // stride-5 covers npp <= 64 (t<13)
                    if (q > last) q = a3;     // idempotent clamp (OR-safe)
                    pf[t] = bm[pp[q] + col];
                }
                haveC = true;
            }
        }
        WG_SYNC();
    }

    int K = s_K;
    bool finished = (K >= POST_TOPN) || (rb1 >= NBLK);
    if (finished) {
        for (int r = K + tid; r < POST_TOPN; r += 1024) {
            float* o = out + ((size_t)b * POST_TOPN + r) * 5;
            o[0] = 0.0f; o[1] = 0.0f; o[2] = 0.0f; o[3] = 0.0f; o[4] = 0.0f;
        }
        if (tid == 0) done[b] = 1;
    } else {
        // persist running mask; picks of the last blocks get their tails
        // (cols >= rb1) OR'd by the NEXT stage's catch-up via picks_g.
        if (tid < NBLK) Sg[tid] = s_S[tid];
    }
    if (tid == 0) kcnt[b] = K;
}

// ---------------------------------------------------------------------------
// Fallback (round-2) NMS kernel — used only if ws_size can't hold the bitmap.
// ---------------------------------------------------------------------------
__global__ __launch_bounds__(1024) void nms_kernel(const float* __restrict__ boxes,
                                                   const u64* __restrict__ keys,
                                                   float* __restrict__ out,
                                                   int N) {
#pragma clang fp contract(off)
    __shared__ float4 kbox[POST_TOPN];
    __shared__ float kar[POST_TOPN];
    __shared__ float4 cbox[64];
    __shared__ float car_s[64];
    __shared__ int supp[64];
    __shared__ int s_cnt;

    int b = blockIdx.x;
    int tid = threadIdx.x;
    const u64* kb = keys + (size_t)b * SORTN;
    const float* bb = boxes + (size_t)b * N * 4;

    if (tid == 0) s_cnt = 0;
    __syncthreads();

    for (int start = 0; start < PRE_TOPN; start += 64) {
        int K = s_cnt;
        if (K >= POST_TOPN) break;
        int csize = min(64, PRE_TOPN - start);

        if (tid < 64) {
            int c = tid;
            if (c < csize) {
                u64 key = kb[start + c];
                int n = (int)(unsigned int)(key & 0xFFFFFFFFULL);
                const float* p = bb + (size_t)n * 4;
                float x1 = p[0], y1 = p[1], x2 = p[2], y2 = p[3];
                cbox[c] = make_float4(x1, y1, x2, y2);
                car_s[c] = ((x2 - x1) + 1.0f) * ((y2 - y1) + 1.0f);
            }
            supp[c] = 0;
        }
        __syncthreads();

        {
            int c = tid & 63;
            int sl = tid >> 6;
            if (c < csize) {
                float4 me = cbox[c];
                float ar = car_s[c];
                int flag = 0;
                for (int kk = sl; kk < K; kk += 16) {
                    float4 k0 = kbox[kk];
                    float a0 = kar[kk];
                    float xx1 = fmaxf(k0.x, me.x);
                    float yy1 = fmaxf(k0.y, me.y);
                    float xx2 = fminf(k0.z, me.z);
                    float yy2 = fminf(k0.w, me.w);
                    float w0 = fmaxf((xx2 - xx1) + 1.0f, 0.0f);
                    float h0 = fmaxf((yy2 - yy1) + 1.0f, 0.0f);
                    float inter0 = w0 * h0;
                    float iou0 = inter0 / ((a0 + ar) - inter0);
                    if (iou0 > 0.7f) { flag = 1; break; }
                }
                if (flag) supp[c] = 1;
            }
        }
        __syncthreads();

        if (tid < 64) {
            int c = tid;
            bool alive = (c < csize) && (supp[c] == 0);
            float4 me = cbox[c];
            float ar = car_s[c];
            int cnt = K;
            u64 m = __ballot(alive);
            while (m != 0 && cnt < POST_TOPN) {
                int i = __ffsll((unsigned long long)m) - 1;
                float ix1 = __shfl(me.x, i);
                float iy1 = __shfl(me.y, i);
                float ix2 = __shfl(me.z, i);
                float iy2 = __shfl(me.w, i);
                float iar = __shfl(ar, i);
                if (c == i) {
                    kbox[cnt] = me;
                    kar[cnt] = ar;
                    float* o = out + ((size_t)b * POST_TOPN + cnt) * 5;
                    o[0] = (float)b; o[1] = me.x; o[2] = me.y; o[3] = me.z; o[4] = me.w;
                }
                if (alive && c > i) {
                    float xx1 = fmaxf(ix1, me.x);
                    float yy1 = fmaxf(iy1, me.y);
                    float xx2 = fminf(ix2, me.z);
                    float yy2 = fminf(iy2, me.w);
                    float w = fmaxf((xx2 - xx1) + 1.0f, 0.0f);
                    float h = fmaxf((yy2 - yy1) + 1.0f, 0.0f);
                    float inter = w * h;
                    float iou = inter / ((iar + ar) - inter);
                    if (iou > 0.7f) alive = false;
                }
                cnt++;
                m = __ballot(alive);
                u64 clearmask = (2ULL << i) - 1ULL;
                m &= ~clearmask;
            }
            if (c == 0) s_cnt = cnt;
        }
        __syncthreads();
    }

    __syncthreads();
    int K = s_cnt;
    for (int r = K + tid; r < POST_TOPN; r += (int)blockDim.x) {
        float* o = out + ((size_t)b * POST_TOPN + r) * 5;
        o[0] = 0.0f; o[1] = 0.0f; o[2] = 0.0f; o[3] = 0.0f; o[4] = 0.0f;
    }
}

// ---------------------------------------------------------------------------
extern "C" void kernel_launch(void* const* d_in, const int* in_sizes, int n_in,
                              void* d_out, int out_size, void* d_ws, size_t ws_size,
                              hipStream_t stream) {
    const float* anchors = (const float*)d_in[0];
    const float* deltas  = (const float*)d_in[1];
    const float* scores  = (const float*)d_in[2];
    float* out = (float*)d_out;

    int N = in_sizes[0] / 4;           // 27380
    int B = in_sizes[2] / N;           // 8

    size_t off = 0;
    auto take = [&](size_t bytes) { size_t o = off; off = (off + bytes + 255) & ~(size_t)255; return o; };
    size_t boxesOff  = take((size_t)B * N * 4 * sizeof(float));
    size_t keysOff   = take((size_t)B * SORTN * sizeof(u64));
    size_t sboxOff   = take((size_t)B * PADN * sizeof(float4));
    size_t bitmapOff = take((size_t)B * TRI_WORDS * sizeof(u64));
    size_t diagOff   = take((size_t)B * PADN * sizeof(u64));
    size_t sd1Off    = take((size_t)B * PADN * sizeof(u64));
    size_t sd2Off    = take((size_t)B * PADN * sizeof(u64));
    size_t SgOff     = take((size_t)B * MASK_WORDS * sizeof(u64));
    size_t pgOff     = take((size_t)B * POST_TOPN * sizeof(int));
    size_t kcntOff   = take((size_t)B * sizeof(int));
    size_t doneOff   = take((size_t)B * sizeof(int));
    bool bitmap_path = (off <= ws_size);

    float* boxes = (float*)((char*)d_ws + boxesOff);
    u64*   keys  = (u64*)((char*)d_ws + keysOff);
    u64* diag    = bitmap_path ? (u64*)((char*)d_ws + diagOff)  : nullptr;
    u64* sd1     = bitmap_path ? (u64*)((char*)d_ws + sd1Off)   : nullptr;
    u64* sd2     = bitmap_path ? (u64*)((char*)d_ws + sd2Off)   : nullptr;
    u64* S_g     = bitmap_path ? (u64*)((char*)d_ws + SgOff)    : nullptr;
    int* pg      = bitmap_path ? (int*)((char*)d_ws + pgOff)    : nullptr;
    int* kcnt    = bitmap_path ? (int*)((char*)d_ws + kcntOff)  : nullptr;
    int* done    = bitmap_path ? (int*)((char*)d_ws + doneOff)  : nullptr;

    dim3 g1((unsigned)((SORTN + 255) / 256), (unsigned)B);
    decode_pack<<<g1, 256, 0, stream>>>(anchors, deltas, scores, boxes, keys, kcnt, done, N);

    // ---- sort: 2048-tiles local sort, then per level k a fused register-
    // orbit global kernel (all j >= 2048) + one LDS local merge (j <= 1024).
    int ntiles = B * NTILE;                       // 128 blocks
    bitonic_local_sort<<<ntiles, 256, 0, stream>>>(keys);
    {
        unsigned g1b = (unsigned)(B * (SORTN >> 1) / 256);
        bitonic_fused_global<1><<<g1b, 256, 0, stream>>>(keys);
        bitonic_local_merge<<<ntiles, 256, 0, stream>>>(keys, 4096);
        unsigned g2b = (unsigned)(B * (SORTN >> 2) / 256);
        bitonic_fused_global<2><<<g2b, 256, 0, stream>>>(keys);
        bitonic_local_merge<<<ntiles, 256, 0, stream>>>(keys, 8192);
        unsigned g3b = (unsigned)(B * (SORTN >> 3) / 256);
        bitonic_fused_global<3><<<g3b, 256, 0, stream>>>(keys);
        bitonic_local_merge<<<ntiles, 256, 0, stream>>>(keys, 16384);
        unsigned g4b = (unsigned)(B * (SORTN >> 4) / 256);
        bitonic_fused_global<4><<<g4b, 256, 0, stream>>>(keys);
        bitonic_local_merge<<<ntiles, 256, 0, stream>>>(keys, 32768);
    }

    if (bitmap_path) {
        float4* sbox = (float4*)((char*)d_ws + sboxOff);
        u64* bitmap  = (u64*)((char*)d_ws + bitmapOff);
        dim3 gg((unsigned)((PADN + 255) / 256), (unsigned)B);
        gather_sorted<<<gg, 256, 0, stream>>>(boxes, keys, sbox, N);

        // Progressive build/scan with per-batch done[] cutoff. Segments in
        // col-block units (even; widths <= 128 per the catch-up's 2-segment
        // mapping).
        const int seg[6] = {0, 48, 64, 88, 120, NBLK};
        for (int s = 0; s < 5; ++s) {
            int c0 = seg[s], c1 = seg[s + 1];
            int p0 = c0 / 2;
            int npair = (c1 - c0) / 2;
            unsigned gy = (unsigned)(((c1 / 2 - 1) >> 1) + 1);   // 256-row chunks
            dim3 gb((unsigned)npair, gy, (unsigned)B);
            build_bitmap<<<gb, 256, 0, stream>>>(sbox, bitmap, diag, sd1, sd2, done, p0);
            scan_nms<<<B, 1024, 0, stream>>>(sbox, bitmap, diag, sd1, sd2, out, S_g, pg, kcnt, done, c0, c1);
        }
    } else {
        nms_kernel<<<B, 1024, 0, stream>>>(boxes, keys, out, N);
    }
}